// Round 4
// baseline (445.207 us; speedup 1.0000x reference)
//
#include <hip/hip_runtime.h>

#define L_SEQ 100
#define E_DIM 100
#define G_DIM 192   // 3*H
#define B_TOT 4096

typedef __attribute__((ext_vector_type(8))) short bf16x8;
typedef __attribute__((ext_vector_type(4))) float f32x4;
typedef __attribute__((ext_vector_type(4))) float float4v;
typedef __attribute__((ext_vector_type(2))) float float2v;
typedef __attribute__((ext_vector_type(4))) unsigned short ushort4v;

static __device__ __forceinline__ unsigned short f2bf(float f) {
    union { float f; unsigned u; } v; v.f = f;
    unsigned r = v.u + 0x7FFFu + ((v.u >> 16) & 1u);  // RNE
    return (unsigned short)(r >> 16);
}
static __device__ __forceinline__ float bf2f(unsigned short u) {
    union { unsigned u; float f; } v; v.u = ((unsigned)u) << 16;
    return v.f;
}
static __device__ __forceinline__ float sigmoidf_(float x) { return 1.f / (1.f + __expf(-x)); }
static __device__ __forceinline__ float tanhf_(float x)    { return 1.f - 2.f / (__expf(2.f * x) + 1.f); }

// ---------------- pre-pass: tiw[m][c16][ntg] = bf16( x@W_in + b_in ), stats[m]={mean,rstd} ----------
// 64 rows per block (4 M-tiles, W_in frags reused). grid = B*L/64, 256 threads.
__global__ __launch_bounds__(256, 4) void ti_proj64(
    const float* __restrict__ x, const float* __restrict__ Win,
    const float* __restrict__ bin, unsigned short* __restrict__ tiw,
    float* __restrict__ stats)
{
    __shared__ unsigned short T[16 * G_DIM];     // [row][c16][ntg] packed, 6144 B
    __shared__ float Ps[4][16], Pss[4][16];

    const int tid = threadIdx.x;
    const int w   = tid >> 6, l = tid & 63;
    const int c16 = l & 15,  g = l >> 4;
    const int m0  = blockIdx.x * 64;
    const int colg = w * 48 + c16;

    // B frags: Win[32kt+8g+j][colg+16nt], zero-padded past k=100
    bf16x8 bw[4][3];
    #pragma unroll
    for (int kt = 0; kt < 4; ++kt)
      #pragma unroll
      for (int nt = 0; nt < 3; ++nt)
        #pragma unroll
        for (int j = 0; j < 8; ++j) {
            int k = 32 * kt + 8 * g + j;
            float v = (k < E_DIM) ? Win[k * G_DIM + colg + 16 * nt] : 0.f;
            bw[kt][nt][j] = (short)f2bf(v);
        }
    float bv[3];
    #pragma unroll
    for (int nt = 0; nt < 3; ++nt) bv[nt] = bin[colg + 16 * nt];

    for (int mt = 0; mt < 4; ++mt) {
        const int mrow = m0 + 16 * mt;
        // A frags from x row mrow+c16
        const float* xr = x + (size_t)(mrow + c16) * E_DIM;
        bf16x8 ax[4];
        #pragma unroll
        for (int kt = 0; kt < 4; ++kt) {
            int k0 = 32 * kt + 8 * g;
            float xv[8];
            if (k0 + 7 < E_DIM) {
                *(float4v*)&xv[0] = *(const float4v*)&xr[k0];
                *(float4v*)&xv[4] = *(const float4v*)&xr[k0 + 4];
            } else {
                #pragma unroll
                for (int j = 0; j < 8; ++j) { int k = k0 + j; xv[j] = (k < E_DIM) ? xr[k] : 0.f; }
            }
            #pragma unroll
            for (int j = 0; j < 8; ++j) ax[kt][j] = (short)f2bf(xv[j]);
        }

        const f32x4 zero = {0.f, 0.f, 0.f, 0.f};
        f32x4 acc[3] = {zero, zero, zero};
        #pragma unroll
        for (int nt = 0; nt < 3; ++nt)
          #pragma unroll
          for (int kt = 0; kt < 4; ++kt)
            acc[nt] = __builtin_amdgcn_mfma_f32_16x16x32_bf16(ax[kt], bw[kt][nt], acc[nt], 0, 0, 0);
        #pragma unroll
        for (int nt = 0; nt < 3; ++nt)
          #pragma unroll
          for (int rr = 0; rr < 4; ++rr) acc[nt][rr] += bv[nt];

        // stats partials (per wave: its 48 cols)
        float s[4], ss[4];
        #pragma unroll
        for (int rr = 0; rr < 4; ++rr) {
            s[rr]  = acc[0][rr] + acc[1][rr] + acc[2][rr];
            ss[rr] = acc[0][rr] * acc[0][rr] + acc[1][rr] * acc[1][rr] + acc[2][rr] * acc[2][rr];
        }
        #pragma unroll
        for (int m = 1; m < 16; m <<= 1)
          #pragma unroll
          for (int rr = 0; rr < 4; ++rr) {
              s[rr]  += __shfl_xor(s[rr], m);
              ss[rr] += __shfl_xor(ss[rr], m);
          }
        if (c16 == 0)
          #pragma unroll
          for (int rr = 0; rr < 4; ++rr) {
              Ps[w][4 * g + rr]  = s[rr];
              Pss[w][4 * g + rr] = ss[rr];
          }

        // T[row][c16][ntg=3w+nt]
        #pragma unroll
        for (int nt = 0; nt < 3; ++nt)
          #pragma unroll
          for (int rr = 0; rr < 4; ++rr)
            T[(4 * g + rr) * G_DIM + c16 * 12 + (3 * w + nt)] = f2bf(acc[nt][rr]);
        __syncthreads();

        if (tid < 16) {
            float sa  = Ps[0][tid] + Ps[1][tid] + Ps[2][tid] + Ps[3][tid];
            float q2  = Pss[0][tid] + Pss[1][tid] + Pss[2][tid] + Pss[3][tid];
            float m   = sa * (1.f / G_DIM);
            float var = (q2 - (float)G_DIM * m * m) * (1.f / (G_DIM - 1));
            stats[2 * (mrow + tid)]     = m;
            stats[2 * (mrow + tid) + 1] = rsqrtf(fmaxf(var, 1e-24f));
        }
        // coalesced store: 3072 u16, 12 per thread (24 B contiguous chunks)
        {
            const unsigned short* src = &T[tid * 12];
            unsigned short* dst = tiw + (size_t)mrow * G_DIM + tid * 12;
            ushort4v v0 = *(const ushort4v*)(src);
            ushort4v v1 = *(const ushort4v*)(src + 4);
            ushort4v v2 = *(const ushort4v*)(src + 8);
            *(ushort4v*)(dst)     = v0;
            *(ushort4v*)(dst + 4) = v1;
            *(ushort4v*)(dst + 8) = v2;
        }
        __syncthreads();
    }
}

// ---------------- recurrent kernel: ONE WAVE owns 4 batch rows, no inter-wave sync ----------------
// Batch row j (j = lane>>4) sits at MFMA tile row 4j. C-frag reg 0 of lane (j,c16) holds
// cols c16+16*ntg of row j. grid = B/4 blocks of 64 threads.
__global__ __launch_bounds__(64) void gru_rec_wave(
    const unsigned short* __restrict__ tiw, const float* __restrict__ stats,
    const float* __restrict__ Wh, const float* __restrict__ bh,
    const float* __restrict__ Wfc, const float* __restrict__ bfc,
    float* __restrict__ out)
{
    __shared__ unsigned short hs[16][72];   // tile-row major; only rows {0,4,8,12} meaningful

    const int l = threadIdx.x, c16 = l & 15, g = l >> 4;
    const int row0 = blockIdx.x * 4;

    // W_h fragments, fully register-resident: bwh[kt][ntg] lane holds Wh[32kt+8g+j][16ntg+c16]
    bf16x8 bwh[2][12];
    #pragma unroll
    for (int kt = 0; kt < 2; ++kt)
      #pragma unroll
      for (int ntg = 0; ntg < 12; ++ntg)
        #pragma unroll
        for (int j = 0; j < 8; ++j)
            bwh[kt][ntg][j] = (short)f2bf(Wh[(32 * kt + 8 * g + j) * G_DIM + 16 * ntg + c16]);

    float bhv[12];
    #pragma unroll
    for (int ntg = 0; ntg < 12; ++ntg) bhv[ntg] = bh[c16 + 16 * ntg];

    float hreg[4] = {0.f, 0.f, 0.f, 0.f};     // fp32 master h: row g, cols c16+16*nt
    #pragma unroll
    for (int nt = 0; nt < 4; ++nt) hs[4 * g][c16 + 16 * nt] = 0;
    __syncthreads();

    const unsigned short* tibase = tiw + (size_t)(row0 + g) * L_SEQ * G_DIM + c16 * 12;
    const float* stbase = stats + (size_t)(row0 + g) * L_SEQ * 2;
    const f32x4 zero = {0.f, 0.f, 0.f, 0.f};

    for (int s = 0; s < 2 * L_SEQ; ++s) {
        const int t = (s < L_SEQ) ? s : s - L_SEQ;
        const bool phase = (s >= L_SEQ);

        // ti: 12 contiguous u16 (permuted layout) — issued early, consumed after MFMA
        const unsigned short* tp = tibase + (size_t)t * G_DIM;
        ushort4v t0 = *(const ushort4v*)(tp);
        ushort4v t1 = *(const ushort4v*)(tp + 4);
        ushort4v t2 = *(const ushort4v*)(tp + 8);
        float mti = 0.f, rti = 1.f;
        if (phase) {
            float2v sv = *(const float2v*)(stbase + 2 * t);
            mti = sv[0]; rti = sv[1];
        }

        // A frags (wave-local LDS; rows != 4j are garbage but only pollute ignored C rows)
        bf16x8 a0 = *(const bf16x8*)&hs[c16][8 * g];
        bf16x8 a1 = *(const bf16x8*)&hs[c16][32 + 8 * g];

        float b[12];
        #pragma unroll
        for (int ntg = 0; ntg < 12; ++ntg) {
            f32x4 acc = __builtin_amdgcn_mfma_f32_16x16x32_bf16(a0, bwh[0][ntg], zero, 0, 0, 0);
            acc       = __builtin_amdgcn_mfma_f32_16x16x32_bf16(a1, bwh[1][ntg], acc,  0, 0, 0);
            b[ntg] = acc[0] + bhv[ntg];
        }

        float mth = 0.f, rth = 1.f;
        if (phase) {
            float sb = 0.f, ssb = 0.f;
            #pragma unroll
            for (int ntg = 0; ntg < 12; ++ntg) { sb += b[ntg]; ssb = fmaf(b[ntg], b[ntg], ssb); }
            #pragma unroll
            for (int m = 1; m < 16; m <<= 1) { sb += __shfl_xor(sb, m); ssb += __shfl_xor(ssb, m); }
            mth = sb * (1.f / G_DIM);
            rth = rsqrtf(fmaxf((ssb - (float)G_DIM * mth * mth) * (1.f / (G_DIM - 1)), 1e-24f));
        }

        float a[12];
        #pragma unroll
        for (int j = 0; j < 4; ++j) {
            a[j]     = bf2f(t0[j]);
            a[j + 4] = bf2f(t1[j]);
            a[j + 8] = bf2f(t2[j]);
        }

        #pragma unroll
        for (int nt = 0; nt < 4; ++nt) {
            float tir = (a[nt]     - mti) * rti;
            float tiz = (a[nt + 4] - mti) * rti;
            float tin = (a[nt + 8] - mti) * rti;
            float thr = (b[nt]     - mth) * rth;
            float thz = (b[nt + 4] - mth) * rth;
            float thn = (b[nt + 8] - mth) * rth;
            float rt = sigmoidf_(tir + thr);
            float zt = sigmoidf_(tiz + thz);
            float nv = tanhf_(tin + rt * thn);
            hreg[nt] = (1.f - zt) * nv + zt * hreg[nt];
            hs[4 * g][c16 + 16 * nt] = f2bf(hreg[nt]);
        }
        __syncthreads();   // single wave: compiles to lgkm fence (orders LDS write -> next read)
    }

    // epilogue: out = h @ W_fc + b_fc
    float p0 = 0.f, p1 = 0.f;
    #pragma unroll
    for (int nt = 0; nt < 4; ++nt) {
        int c = c16 + 16 * nt;
        p0 = fmaf(hreg[nt], Wfc[2 * c],     p0);
        p1 = fmaf(hreg[nt], Wfc[2 * c + 1], p1);
    }
    #pragma unroll
    for (int m = 1; m < 16; m <<= 1) { p0 += __shfl_xor(p0, m); p1 += __shfl_xor(p1, m); }
    if (c16 == 0) {
        out[(row0 + g) * 2 + 0] = p0 + bfc[0];
        out[(row0 + g) * 2 + 1] = p1 + bfc[1];
    }
}

// ---------------- fallback (ws too small): monolithic, ti computed inline ----------------
__global__ __launch_bounds__(256, 4) void gru_rec_fallback(
    const float* __restrict__ x,
    const float* __restrict__ Win, const float* __restrict__ bin,
    const float* __restrict__ Wh,  const float* __restrict__ bh,
    const float* __restrict__ Wfc, const float* __restrict__ bfc,
    float* __restrict__ out)
{
    __shared__ float S_th[16][194];
    __shared__ float S_ti[16][194];
    __shared__ unsigned short h_bf[16][72];
    __shared__ float bh_l[G_DIM], bin_l[G_DIM];

    const int tid = threadIdx.x;
    const int w   = tid >> 6, l = tid & 63;
    const int c16 = l & 15,  g = l >> 4;
    const int colg = w * 48 + c16;
    const int row0 = blockIdx.x * 4;
    const int row  = w, q = l;

    if (tid < G_DIM) { bh_l[tid] = bh[tid]; bin_l[tid] = bin[tid]; }
    for (int i = tid; i < 16 * 72; i += 256) (&h_bf[0][0])[i] = 0;

    bf16x8 bwh[2][3], bwin[4][3];
    #pragma unroll
    for (int kt = 0; kt < 2; ++kt)
      #pragma unroll
      for (int nt = 0; nt < 3; ++nt)
        #pragma unroll
        for (int j = 0; j < 8; ++j)
            bwh[kt][nt][j] = (short)f2bf(Wh[(32 * kt + 8 * g + j) * G_DIM + colg + 16 * nt]);
    #pragma unroll
    for (int kt = 0; kt < 4; ++kt)
      #pragma unroll
      for (int nt = 0; nt < 3; ++nt)
        #pragma unroll
        for (int j = 0; j < 8; ++j) {
            int k = 32 * kt + 8 * g + j;
            float v = (k < E_DIM) ? Win[k * G_DIM + colg + 16 * nt] : 0.f;
            bwin[kt][nt][j] = (short)f2bf(v);
        }
    int xr = row0 + c16; if (xr > B_TOT - 1) xr = B_TOT - 1;
    const float* xlane = x + (size_t)xr * (L_SEQ * E_DIM);

    float hq = 0.f;
    __syncthreads();

    for (int s = 0; s < 2 * L_SEQ; ++s) {
        const int t = (s < L_SEQ) ? s : s - L_SEQ;
        const bool phase = (s >= L_SEQ);

        bf16x8 ah0 = *(const bf16x8*)&h_bf[c16][8 * g];
        bf16x8 ah1 = *(const bf16x8*)&h_bf[c16][32 + 8 * g];
        const f32x4 zero = {0.f, 0.f, 0.f, 0.f};
        f32x4 acch[3], acci[3];
        #pragma unroll
        for (int nt = 0; nt < 3; ++nt) {
            acch[nt] = __builtin_amdgcn_mfma_f32_16x16x32_bf16(ah0, bwh[0][nt], zero,     0, 0, 0);
            acch[nt] = __builtin_amdgcn_mfma_f32_16x16x32_bf16(ah1, bwh[1][nt], acch[nt], 0, 0, 0);
        }
        {
            bf16x8 axx[4];
            const float* xp = xlane + t * E_DIM;
            #pragma unroll
            for (int kt = 0; kt < 4; ++kt) {
                int k0 = 32 * kt + 8 * g;
                float xv[8];
                if (k0 + 7 < E_DIM) {
                    *(float4v*)&xv[0] = *(const float4v*)&xp[k0];
                    *(float4v*)&xv[4] = *(const float4v*)&xp[k0 + 4];
                } else {
                    #pragma unroll
                    for (int j = 0; j < 8; ++j) { int k = k0 + j; xv[j] = (k < E_DIM) ? xp[k] : 0.f; }
                }
                #pragma unroll
                for (int j = 0; j < 8; ++j) axx[kt][j] = (short)f2bf(xv[j]);
            }
            #pragma unroll
            for (int nt = 0; nt < 3; ++nt) {
                acci[nt] = zero;
                #pragma unroll
                for (int kt = 0; kt < 4; ++kt)
                    acci[nt] = __builtin_amdgcn_mfma_f32_16x16x32_bf16(axx[kt], bwin[kt][nt], acci[nt], 0, 0, 0);
            }
        }
        #pragma unroll
        for (int nt = 0; nt < 3; ++nt)
          #pragma unroll
          for (int rr = 0; rr < 4; ++rr) {
              S_th[4 * g + rr][colg + 16 * nt] = acch[nt][rr];
              S_ti[4 * g + rr][colg + 16 * nt] = acci[nt][rr];
          }
        __syncthreads();

        float a[3], b[3];
        #pragma unroll
        for (int i = 0; i < 3; ++i) {
            int c = q + 64 * i;
            a[i] = S_ti[row][c] + bin_l[c];
            b[i] = S_th[row][c] + bh_l[c];
        }
        float mti = 0.f, rti = 1.f, mth = 0.f, rth = 1.f;
        if (phase) {
            float sti = a[0] + a[1] + a[2], ssti = a[0]*a[0] + a[1]*a[1] + a[2]*a[2];
            float sth = b[0] + b[1] + b[2], ssth = b[0]*b[0] + b[1]*b[1] + b[2]*b[2];
            #pragma unroll
            for (int m = 1; m < 64; m <<= 1) {
                sti += __shfl_xor(sti, m); ssti += __shfl_xor(ssti, m);
                sth += __shfl_xor(sth, m); ssth += __shfl_xor(ssth, m);
            }
            mti = sti * (1.f / G_DIM);
            rti = rsqrtf(fmaxf((ssti - (float)G_DIM * mti * mti) * (1.f / (G_DIM - 1)), 1e-24f));
            mth = sth * (1.f / G_DIM);
            rth = rsqrtf(fmaxf((ssth - (float)G_DIM * mth * mth) * (1.f / (G_DIM - 1)), 1e-24f));
        }
        float tir = (a[0] - mti) * rti, tiz = (a[1] - mti) * rti, tin = (a[2] - mti) * rti;
        float thr = (b[0] - mth) * rth, thz = (b[1] - mth) * rth, thn = (b[2] - mth) * rth;
        float rt = sigmoidf_(tir + thr);
        float zt = sigmoidf_(tiz + thz);
        float nv = tanhf_(tin + rt * thn);
        hq = (1.f - zt) * nv + zt * hq;
        h_bf[row][q] = f2bf(hq);
        __syncthreads();
    }

    float p0 = hq * Wfc[2 * q], p1 = hq * Wfc[2 * q + 1];
    #pragma unroll
    for (int m = 1; m < 64; m <<= 1) { p0 += __shfl_xor(p0, m); p1 += __shfl_xor(p1, m); }
    if (q == 0) {
        out[(row0 + row) * 2 + 0] = p0 + bfc[0];
        out[(row0 + row) * 2 + 1] = p1 + bfc[1];
    }
}

extern "C" void kernel_launch(void* const* d_in, const int* in_sizes, int n_in,
                              void* d_out, int out_size, void* d_ws, size_t ws_size,
                              hipStream_t stream) {
    const float* x   = (const float*)d_in[0];
    const float* Win = (const float*)d_in[1];
    const float* bin = (const float*)d_in[2];
    const float* Wh  = (const float*)d_in[3];
    const float* bh  = (const float*)d_in[4];
    const float* Wfc = (const float*)d_in[5];
    const float* bfc = (const float*)d_in[6];
    float* out = (float*)d_out;

    const size_t stats_b = (size_t)B_TOT * L_SEQ * 2 * sizeof(float);              // 3.28 MB
    const size_t tiw_b   = (size_t)B_TOT * L_SEQ * G_DIM * sizeof(unsigned short); // 157.3 MB

    if (ws_size >= stats_b + tiw_b) {
        float* stats = (float*)d_ws;
        unsigned short* tiw = (unsigned short*)((char*)d_ws + stats_b);
        ti_proj64<<<dim3(B_TOT * L_SEQ / 64), dim3(256), 0, stream>>>(x, Win, bin, tiw, stats);
        gru_rec_wave<<<dim3(B_TOT / 4), dim3(64), 0, stream>>>(tiw, stats, Wh, bh, Wfc, bfc, out);
    } else {
        gru_rec_fallback<<<dim3(B_TOT / 4), dim3(256), 0, stream>>>(
            x, Win, bin, Wh, bh, Wfc, bfc, out);
    }
}

// Round 5
// 375.589 us; speedup vs baseline: 1.1854x; 1.1854x over previous
//
#include <hip/hip_runtime.h>

#define L_SEQ 100
#define E_DIM 100
#define G_DIM 192   // 3*H
#define B_TOT 4096

typedef __attribute__((ext_vector_type(8))) short bf16x8;
typedef __attribute__((ext_vector_type(4))) float f32x4;
typedef __attribute__((ext_vector_type(4))) float float4v;
typedef __attribute__((ext_vector_type(2))) float float2v;
typedef __attribute__((ext_vector_type(4))) unsigned short ushort4v;

static __device__ __forceinline__ unsigned short f2bf(float f) {
    union { float f; unsigned u; } v; v.f = f;
    unsigned r = v.u + 0x7FFFu + ((v.u >> 16) & 1u);  // RNE
    return (unsigned short)(r >> 16);
}
static __device__ __forceinline__ float bf2f(unsigned short u) {
    union { unsigned u; float f; } v; v.u = ((unsigned)u) << 16;
    return v.f;
}
static __device__ __forceinline__ float sigmoidf_(float x) { return 1.f / (1.f + __expf(-x)); }
static __device__ __forceinline__ float tanhf_(float x)    { return 1.f - 2.f / (__expf(2.f * x) + 1.f); }

// 16-lane (DPP-row) sum reduce: pure VALU, no DS ops on the chain
template<int CTRL>
static __device__ __forceinline__ float dppadd(float x) {
    union { float f; int i; } s, d;
    s.f = x;
    d.i = __builtin_amdgcn_update_dpp(0, s.i, CTRL, 0xF, 0xF, false);
    return x + d.f;
}
static __device__ __forceinline__ float redrow16(float x) {
    x = dppadd<0x128>(x);   // row_ror:8
    x = dppadd<0x124>(x);   // row_ror:4
    x = dppadd<0x122>(x);   // row_ror:2
    x = dppadd<0x121>(x);   // row_ror:1
    return x;
}

// ---------------- pre-pass: tiw[m][c16][ntg] = bf16( x@W_in + b_in ), stats[m]={mean,rstd} ----------
__global__ __launch_bounds__(256, 4) void ti_proj64(
    const float* __restrict__ x, const float* __restrict__ Win,
    const float* __restrict__ bin, unsigned short* __restrict__ tiw,
    float* __restrict__ stats)
{
    __shared__ unsigned short T[16 * G_DIM];
    __shared__ float Ps[4][16], Pss[4][16];

    const int tid = threadIdx.x;
    const int w   = tid >> 6, l = tid & 63;
    const int c16 = l & 15,  g = l >> 4;
    const int m0  = blockIdx.x * 64;
    const int colg = w * 48 + c16;

    bf16x8 bw[4][3];
    #pragma unroll
    for (int kt = 0; kt < 4; ++kt)
      #pragma unroll
      for (int nt = 0; nt < 3; ++nt)
        #pragma unroll
        for (int j = 0; j < 8; ++j) {
            int k = 32 * kt + 8 * g + j;
            float v = (k < E_DIM) ? Win[k * G_DIM + colg + 16 * nt] : 0.f;
            bw[kt][nt][j] = (short)f2bf(v);
        }
    float bv[3];
    #pragma unroll
    for (int nt = 0; nt < 3; ++nt) bv[nt] = bin[colg + 16 * nt];

    for (int mt = 0; mt < 4; ++mt) {
        const int mrow = m0 + 16 * mt;
        const float* xr = x + (size_t)(mrow + c16) * E_DIM;
        bf16x8 ax[4];
        #pragma unroll
        for (int kt = 0; kt < 4; ++kt) {
            int k0 = 32 * kt + 8 * g;
            float xv[8];
            if (k0 + 7 < E_DIM) {
                *(float4v*)&xv[0] = *(const float4v*)&xr[k0];
                *(float4v*)&xv[4] = *(const float4v*)&xr[k0 + 4];
            } else {
                #pragma unroll
                for (int j = 0; j < 8; ++j) { int k = k0 + j; xv[j] = (k < E_DIM) ? xr[k] : 0.f; }
            }
            #pragma unroll
            for (int j = 0; j < 8; ++j) ax[kt][j] = (short)f2bf(xv[j]);
        }

        const f32x4 zero = {0.f, 0.f, 0.f, 0.f};
        f32x4 acc[3] = {zero, zero, zero};
        #pragma unroll
        for (int nt = 0; nt < 3; ++nt)
          #pragma unroll
          for (int kt = 0; kt < 4; ++kt)
            acc[nt] = __builtin_amdgcn_mfma_f32_16x16x32_bf16(ax[kt], bw[kt][nt], acc[nt], 0, 0, 0);
        #pragma unroll
        for (int nt = 0; nt < 3; ++nt)
          #pragma unroll
          for (int rr = 0; rr < 4; ++rr) acc[nt][rr] += bv[nt];

        float s[4], ss[4];
        #pragma unroll
        for (int rr = 0; rr < 4; ++rr) {
            s[rr]  = acc[0][rr] + acc[1][rr] + acc[2][rr];
            ss[rr] = acc[0][rr] * acc[0][rr] + acc[1][rr] * acc[1][rr] + acc[2][rr] * acc[2][rr];
        }
        #pragma unroll
        for (int rr = 0; rr < 4; ++rr) { s[rr] = redrow16(s[rr]); ss[rr] = redrow16(ss[rr]); }
        if (c16 == 0)
          #pragma unroll
          for (int rr = 0; rr < 4; ++rr) {
              Ps[w][4 * g + rr]  = s[rr];
              Pss[w][4 * g + rr] = ss[rr];
          }

        #pragma unroll
        for (int nt = 0; nt < 3; ++nt)
          #pragma unroll
          for (int rr = 0; rr < 4; ++rr)
            T[(4 * g + rr) * G_DIM + c16 * 12 + (3 * w + nt)] = f2bf(acc[nt][rr]);
        __syncthreads();

        if (tid < 16) {
            float sa  = Ps[0][tid] + Ps[1][tid] + Ps[2][tid] + Ps[3][tid];
            float q2  = Pss[0][tid] + Pss[1][tid] + Pss[2][tid] + Pss[3][tid];
            float m   = sa * (1.f / G_DIM);
            float var = (q2 - (float)G_DIM * m * m) * (1.f / (G_DIM - 1));
            stats[2 * (mrow + tid)]     = m;
            stats[2 * (mrow + tid) + 1] = rsqrtf(fmaxf(var, 1e-24f));
        }
        {
            const unsigned short* src = &T[tid * 12];
            unsigned short* dst = tiw + (size_t)mrow * G_DIM + tid * 12;
            ushort4v v0 = *(const ushort4v*)(src);
            ushort4v v1 = *(const ushort4v*)(src + 4);
            ushort4v v2 = *(const ushort4v*)(src + 8);
            *(ushort4v*)(dst)     = v0;
            *(ushort4v*)(dst + 4) = v1;
            *(ushort4v*)(dst + 8) = v2;
        }
        __syncthreads();
    }
}

// ---------------- recurrent kernel: 1 wave / 4 rows, 2-deep prefetch, DPP reduce, no barriers ------
struct TiBuf { ushort4v t0, t1, t2; float2v sv; };

static __device__ __forceinline__ void ti_prefetch(
    TiBuf& b, const unsigned short* __restrict__ tibase,
    const float* __restrict__ stbase, int s2)
{
    int t2 = (s2 < L_SEQ) ? s2 : (s2 - L_SEQ);
    if (t2 > L_SEQ - 1) t2 = L_SEQ - 1;
    const unsigned short* tp = tibase + (size_t)t2 * G_DIM;
    b.t0 = *(const ushort4v*)(tp);
    b.t1 = *(const ushort4v*)(tp + 4);
    b.t2 = *(const ushort4v*)(tp + 8);
    b.sv = *(const float2v*)(stbase + 2 * t2);
}

template<bool PHASE>
static __device__ __forceinline__ void gstep(
    TiBuf& buf, const unsigned short* __restrict__ tibase,
    const float* __restrict__ stbase, int s,
    unsigned short (&hs)[16][72],
    const bf16x8 (&bwh)[2][12], const float (&bhv)[12],
    float (&hreg)[4], int c16, int g)
{
    // consume prefetched ti (loaded 2 steps ago — vmcnt wait is counted, not 0)
    float a[12];
    #pragma unroll
    for (int j = 0; j < 4; ++j) {
        a[j]     = bf2f(buf.t0[j]);
        a[j + 4] = bf2f(buf.t1[j]);
        a[j + 8] = bf2f(buf.t2[j]);
    }
    float mti = 0.f, rti = 1.f;
    if constexpr (PHASE) { mti = buf.sv[0]; rti = buf.sv[1]; }

    // reissue this buffer for step s+2
    ti_prefetch(buf, tibase, stbase, s + 2);

    // h A-frags from wave-local LDS (compiler orders via lgkmcnt; single wave)
    bf16x8 a0 = *(const bf16x8*)&hs[c16][8 * g];
    bf16x8 a1 = *(const bf16x8*)&hs[c16][32 + 8 * g];

    const f32x4 zero = {0.f, 0.f, 0.f, 0.f};
    float b[12];
    #pragma unroll
    for (int ntg = 0; ntg < 12; ++ntg) {
        f32x4 acc = __builtin_amdgcn_mfma_f32_16x16x32_bf16(a0, bwh[0][ntg], zero, 0, 0, 0);
        acc       = __builtin_amdgcn_mfma_f32_16x16x32_bf16(a1, bwh[1][ntg], acc,  0, 0, 0);
        b[ntg] = acc[0] + bhv[ntg];
    }

    float mth = 0.f, rth = 1.f;
    if constexpr (PHASE) {
        float sb = 0.f, ssb = 0.f;
        #pragma unroll
        for (int ntg = 0; ntg < 12; ++ntg) { sb += b[ntg]; ssb = fmaf(b[ntg], b[ntg], ssb); }
        sb  = redrow16(sb);
        ssb = redrow16(ssb);
        mth = sb * (1.f / G_DIM);
        rth = rsqrtf(fmaxf((ssb - (float)G_DIM * mth * mth) * (1.f / (G_DIM - 1)), 1e-24f));
    }

    #pragma unroll
    for (int nt = 0; nt < 4; ++nt) {
        float tir, tiz, tin, thr, thz, thn;
        if constexpr (PHASE) {
            tir = (a[nt]     - mti) * rti;
            tiz = (a[nt + 4] - mti) * rti;
            tin = (a[nt + 8] - mti) * rti;
            thr = (b[nt]     - mth) * rth;
            thz = (b[nt + 4] - mth) * rth;
            thn = (b[nt + 8] - mth) * rth;
        } else {
            tir = a[nt]; tiz = a[nt + 4]; tin = a[nt + 8];
            thr = b[nt]; thz = b[nt + 4]; thn = b[nt + 8];
        }
        float rt = sigmoidf_(tir + thr);
        float zt = sigmoidf_(tiz + thz);
        float nv = tanhf_(tin + rt * thn);
        hreg[nt] = (1.f - zt) * nv + zt * hreg[nt];
        hs[4 * g][c16 + 16 * nt] = f2bf(hreg[nt]);
    }
}

__global__ __launch_bounds__(64) void gru_rec_wave(
    const unsigned short* __restrict__ tiw, const float* __restrict__ stats,
    const float* __restrict__ Wh, const float* __restrict__ bh,
    const float* __restrict__ Wfc, const float* __restrict__ bfc,
    float* __restrict__ out)
{
    __shared__ unsigned short hs[16][72];

    const int l = threadIdx.x, c16 = l & 15, g = l >> 4;
    const int row0 = blockIdx.x * 4;

    bf16x8 bwh[2][12];
    #pragma unroll
    for (int kt = 0; kt < 2; ++kt)
      #pragma unroll
      for (int ntg = 0; ntg < 12; ++ntg)
        #pragma unroll
        for (int j = 0; j < 8; ++j)
            bwh[kt][ntg][j] = (short)f2bf(Wh[(32 * kt + 8 * g + j) * G_DIM + 16 * ntg + c16]);

    float bhv[12];
    #pragma unroll
    for (int ntg = 0; ntg < 12; ++ntg) bhv[ntg] = bh[c16 + 16 * ntg];

    float hreg[4] = {0.f, 0.f, 0.f, 0.f};
    #pragma unroll
    for (int nt = 0; nt < 4; ++nt) hs[4 * g][c16 + 16 * nt] = 0;

    const unsigned short* tibase = tiw + (size_t)(row0 + g) * L_SEQ * G_DIM + c16 * 12;
    const float* stbase = stats + (size_t)(row0 + g) * L_SEQ * 2;

    TiBuf bufA, bufB;
    ti_prefetch(bufA, tibase, stbase, 0);
    ti_prefetch(bufB, tibase, stbase, 1);

    #pragma unroll 1
    for (int s = 0; s < L_SEQ; s += 2) {
        gstep<false>(bufA, tibase, stbase, s,     hs, bwh, bhv, hreg, c16, g);
        gstep<false>(bufB, tibase, stbase, s + 1, hs, bwh, bhv, hreg, c16, g);
    }
    #pragma unroll 1
    for (int s = L_SEQ; s < 2 * L_SEQ; s += 2) {
        gstep<true>(bufA, tibase, stbase, s,     hs, bwh, bhv, hreg, c16, g);
        gstep<true>(bufB, tibase, stbase, s + 1, hs, bwh, bhv, hreg, c16, g);
    }

    // epilogue: out = h @ W_fc + b_fc (DPP reduce over c16)
    float p0 = 0.f, p1 = 0.f;
    #pragma unroll
    for (int nt = 0; nt < 4; ++nt) {
        int c = c16 + 16 * nt;
        p0 = fmaf(hreg[nt], Wfc[2 * c],     p0);
        p1 = fmaf(hreg[nt], Wfc[2 * c + 1], p1);
    }
    p0 = redrow16(p0);
    p1 = redrow16(p1);
    if (c16 == 0) {
        out[(row0 + g) * 2 + 0] = p0 + bfc[0];
        out[(row0 + g) * 2 + 1] = p1 + bfc[1];
    }
}

// ---------------- fallback (ws too small): monolithic, ti computed inline ----------------
__global__ __launch_bounds__(256, 4) void gru_rec_fallback(
    const float* __restrict__ x,
    const float* __restrict__ Win, const float* __restrict__ bin,
    const float* __restrict__ Wh,  const float* __restrict__ bh,
    const float* __restrict__ Wfc, const float* __restrict__ bfc,
    float* __restrict__ out)
{
    __shared__ float S_th[16][194];
    __shared__ float S_ti[16][194];
    __shared__ unsigned short h_bf[16][72];
    __shared__ float bh_l[G_DIM], bin_l[G_DIM];

    const int tid = threadIdx.x;
    const int w   = tid >> 6, l = tid & 63;
    const int c16 = l & 15,  g = l >> 4;
    const int colg = w * 48 + c16;
    const int row0 = blockIdx.x * 4;
    const int row  = w, q = l;

    if (tid < G_DIM) { bh_l[tid] = bh[tid]; bin_l[tid] = bin[tid]; }
    for (int i = tid; i < 16 * 72; i += 256) (&h_bf[0][0])[i] = 0;

    bf16x8 bwh[2][3], bwin[4][3];
    #pragma unroll
    for (int kt = 0; kt < 2; ++kt)
      #pragma unroll
      for (int nt = 0; nt < 3; ++nt)
        #pragma unroll
        for (int j = 0; j < 8; ++j)
            bwh[kt][nt][j] = (short)f2bf(Wh[(32 * kt + 8 * g + j) * G_DIM + colg + 16 * nt]);
    #pragma unroll
    for (int kt = 0; kt < 4; ++kt)
      #pragma unroll
      for (int nt = 0; nt < 3; ++nt)
        #pragma unroll
        for (int j = 0; j < 8; ++j) {
            int k = 32 * kt + 8 * g + j;
            float v = (k < E_DIM) ? Win[k * G_DIM + colg + 16 * nt] : 0.f;
            bwin[kt][nt][j] = (short)f2bf(v);
        }
    int xr = row0 + c16; if (xr > B_TOT - 1) xr = B_TOT - 1;
    const float* xlane = x + (size_t)xr * (L_SEQ * E_DIM);

    float hq = 0.f;
    __syncthreads();

    for (int s = 0; s < 2 * L_SEQ; ++s) {
        const int t = (s < L_SEQ) ? s : s - L_SEQ;
        const bool phase = (s >= L_SEQ);

        bf16x8 ah0 = *(const bf16x8*)&h_bf[c16][8 * g];
        bf16x8 ah1 = *(const bf16x8*)&h_bf[c16][32 + 8 * g];
        const f32x4 zero = {0.f, 0.f, 0.f, 0.f};
        f32x4 acch[3], acci[3];
        #pragma unroll
        for (int nt = 0; nt < 3; ++nt) {
            acch[nt] = __builtin_amdgcn_mfma_f32_16x16x32_bf16(ah0, bwh[0][nt], zero,     0, 0, 0);
            acch[nt] = __builtin_amdgcn_mfma_f32_16x16x32_bf16(ah1, bwh[1][nt], acch[nt], 0, 0, 0);
        }
        {
            bf16x8 axx[4];
            const float* xp = xlane + t * E_DIM;
            #pragma unroll
            for (int kt = 0; kt < 4; ++kt) {
                int k0 = 32 * kt + 8 * g;
                float xv[8];
                if (k0 + 7 < E_DIM) {
                    *(float4v*)&xv[0] = *(const float4v*)&xp[k0];
                    *(float4v*)&xv[4] = *(const float4v*)&xp[k0 + 4];
                } else {
                    #pragma unroll
                    for (int j = 0; j < 8; ++j) { int k = k0 + j; xv[j] = (k < E_DIM) ? xp[k] : 0.f; }
                }
                #pragma unroll
                for (int j = 0; j < 8; ++j) axx[kt][j] = (short)f2bf(xv[j]);
            }
            #pragma unroll
            for (int nt = 0; nt < 3; ++nt) {
                acci[nt] = zero;
                #pragma unroll
                for (int kt = 0; kt < 4; ++kt)
                    acci[nt] = __builtin_amdgcn_mfma_f32_16x16x32_bf16(axx[kt], bwin[kt][nt], acci[nt], 0, 0, 0);
            }
        }
        #pragma unroll
        for (int nt = 0; nt < 3; ++nt)
          #pragma unroll
          for (int rr = 0; rr < 4; ++rr) {
              S_th[4 * g + rr][colg + 16 * nt] = acch[nt][rr];
              S_ti[4 * g + rr][colg + 16 * nt] = acci[nt][rr];
          }
        __syncthreads();

        float a[3], b[3];
        #pragma unroll
        for (int i = 0; i < 3; ++i) {
            int c = q + 64 * i;
            a[i] = S_ti[row][c] + bin_l[c];
            b[i] = S_th[row][c] + bh_l[c];
        }
        float mti = 0.f, rti = 1.f, mth = 0.f, rth = 1.f;
        if (phase) {
            float sti = a[0] + a[1] + a[2], ssti = a[0]*a[0] + a[1]*a[1] + a[2]*a[2];
            float sth = b[0] + b[1] + b[2], ssth = b[0]*b[0] + b[1]*b[1] + b[2]*b[2];
            #pragma unroll
            for (int m = 1; m < 64; m <<= 1) {
                sti += __shfl_xor(sti, m); ssti += __shfl_xor(ssti, m);
                sth += __shfl_xor(sth, m); ssth += __shfl_xor(ssth, m);
            }
            mti = sti * (1.f / G_DIM);
            rti = rsqrtf(fmaxf((ssti - (float)G_DIM * mti * mti) * (1.f / (G_DIM - 1)), 1e-24f));
            mth = sth * (1.f / G_DIM);
            rth = rsqrtf(fmaxf((ssth - (float)G_DIM * mth * mth) * (1.f / (G_DIM - 1)), 1e-24f));
        }
        float tir = (a[0] - mti) * rti, tiz = (a[1] - mti) * rti, tin = (a[2] - mti) * rti;
        float thr = (b[0] - mth) * rth, thz = (b[1] - mth) * rth, thn = (b[2] - mth) * rth;
        float rt = sigmoidf_(tir + thr);
        float zt = sigmoidf_(tiz + thz);
        float nv = tanhf_(tin + rt * thn);
        hq = (1.f - zt) * nv + zt * hq;
        h_bf[row][q] = f2bf(hq);
        __syncthreads();
    }

    float p0 = hq * Wfc[2 * q], p1 = hq * Wfc[2 * q + 1];
    #pragma unroll
    for (int m = 1; m < 64; m <<= 1) { p0 += __shfl_xor(p0, m); p1 += __shfl_xor(p1, m); }
    if (q == 0) {
        out[(row0 + row) * 2 + 0] = p0 + bfc[0];
        out[(row0 + row) * 2 + 1] = p1 + bfc[1];
    }
}

extern "C" void kernel_launch(void* const* d_in, const int* in_sizes, int n_in,
                              void* d_out, int out_size, void* d_ws, size_t ws_size,
                              hipStream_t stream) {
    const float* x   = (const float*)d_in[0];
    const float* Win = (const float*)d_in[1];
    const float* bin = (const float*)d_in[2];
    const float* Wh  = (const float*)d_in[3];
    const float* bh  = (const float*)d_in[4];
    const float* Wfc = (const float*)d_in[5];
    const float* bfc = (const float*)d_in[6];
    float* out = (float*)d_out;

    const size_t stats_b = (size_t)B_TOT * L_SEQ * 2 * sizeof(float);              // 3.28 MB
    const size_t tiw_b   = (size_t)B_TOT * L_SEQ * G_DIM * sizeof(unsigned short); // 157.3 MB

    if (ws_size >= stats_b + tiw_b) {
        float* stats = (float*)d_ws;
        unsigned short* tiw = (unsigned short*)((char*)d_ws + stats_b);
        ti_proj64<<<dim3(B_TOT * L_SEQ / 64), dim3(256), 0, stream>>>(x, Win, bin, tiw, stats);
        gru_rec_wave<<<dim3(B_TOT / 4), dim3(64), 0, stream>>>(tiw, stats, Wh, bh, Wfc, bfc, out);
    } else {
        gru_rec_fallback<<<dim3(B_TOT / 4), dim3(256), 0, stream>>>(
            x, Win, bin, Wh, bh, Wfc, bfc, out);
    }
}

// Round 6
// 265.876 us; speedup vs baseline: 1.6745x; 1.4126x over previous
//
#include <hip/hip_runtime.h>

#define L_SEQ 100
#define E_DIM 100
#define G_DIM 192   // 3*H
#define B_TOT 4096

typedef __attribute__((ext_vector_type(8))) short bf16x8;
typedef __attribute__((ext_vector_type(4))) float f32x4;
typedef __attribute__((ext_vector_type(4))) float float4v;
typedef __attribute__((ext_vector_type(2))) float float2v;
typedef __attribute__((ext_vector_type(4))) unsigned short ushort4v;

static __device__ __forceinline__ unsigned short f2bf(float f) {
    union { float f; unsigned u; } v; v.f = f;
    unsigned r = v.u + 0x7FFFu + ((v.u >> 16) & 1u);  // RNE
    return (unsigned short)(r >> 16);
}
static __device__ __forceinline__ float bf2f(unsigned short u) {
    union { unsigned u; float f; } v; v.u = ((unsigned)u) << 16;
    return v.f;
}
static __device__ __forceinline__ float sigmoidf_(float x) { return 1.f / (1.f + __expf(-x)); }
static __device__ __forceinline__ float tanhf_(float x)    { return 1.f - 2.f / (__expf(2.f * x) + 1.f); }

// raw barrier: drains LDS ops only (keeps global prefetch in flight — no vmcnt drain)
#define BAR() do { \
    asm volatile("s_waitcnt lgkmcnt(0)" ::: "memory"); \
    __builtin_amdgcn_s_barrier(); \
    asm volatile("" ::: "memory"); \
} while (0)

// ---------------- pre-pass: tiw = bf16( x @ W_in + b_in ) in rec-lane-permuted layout ----------------
// stored offset for gate col c: ntg=c>>4 -> off = 48*(ntg&3) + 12*((c&15)>>2) + 4*(ntg>>2) + (c&3)
__global__ __launch_bounds__(256, 4) void ti_proj64(
    const float* __restrict__ x, const float* __restrict__ Win,
    const float* __restrict__ bin, unsigned short* __restrict__ tiw,
    float* __restrict__ stats)
{
    __shared__ unsigned short T[16 * G_DIM];
    __shared__ float Ps[4][16], Pss[4][16];

    const int tid = threadIdx.x;
    const int w   = tid >> 6, l = tid & 63;
    const int c16 = l & 15,  g = l >> 4;
    const int m0  = blockIdx.x * 64;
    const int colg = w * 48 + c16;

    bf16x8 bw[4][3];
    #pragma unroll
    for (int kt = 0; kt < 4; ++kt)
      #pragma unroll
      for (int nt = 0; nt < 3; ++nt)
        #pragma unroll
        for (int j = 0; j < 8; ++j) {
            int k = 32 * kt + 8 * g + j;
            float v = (k < E_DIM) ? Win[k * G_DIM + colg + 16 * nt] : 0.f;
            bw[kt][nt][j] = (short)f2bf(v);
        }
    float bv[3];
    #pragma unroll
    for (int nt = 0; nt < 3; ++nt) bv[nt] = bin[colg + 16 * nt];

    for (int mt = 0; mt < 4; ++mt) {
        const int mrow = m0 + 16 * mt;
        const float* xr = x + (size_t)(mrow + c16) * E_DIM;
        bf16x8 ax[4];
        #pragma unroll
        for (int kt = 0; kt < 4; ++kt) {
            int k0 = 32 * kt + 8 * g;
            float xv[8];
            if (k0 + 7 < E_DIM) {
                *(float4v*)&xv[0] = *(const float4v*)&xr[k0];
                *(float4v*)&xv[4] = *(const float4v*)&xr[k0 + 4];
            } else {
                #pragma unroll
                for (int j = 0; j < 8; ++j) { int k = k0 + j; xv[j] = (k < E_DIM) ? xr[k] : 0.f; }
            }
            #pragma unroll
            for (int j = 0; j < 8; ++j) ax[kt][j] = (short)f2bf(xv[j]);
        }

        const f32x4 zero = {0.f, 0.f, 0.f, 0.f};
        f32x4 acc[3] = {zero, zero, zero};
        #pragma unroll
        for (int nt = 0; nt < 3; ++nt)
          #pragma unroll
          for (int kt = 0; kt < 4; ++kt)
            acc[nt] = __builtin_amdgcn_mfma_f32_16x16x32_bf16(ax[kt], bw[kt][nt], acc[nt], 0, 0, 0);
        #pragma unroll
        for (int nt = 0; nt < 3; ++nt)
          #pragma unroll
          for (int rr = 0; rr < 4; ++rr) acc[nt][rr] += bv[nt];

        float s[4], ss[4];
        #pragma unroll
        for (int rr = 0; rr < 4; ++rr) {
            s[rr]  = acc[0][rr] + acc[1][rr] + acc[2][rr];
            ss[rr] = acc[0][rr] * acc[0][rr] + acc[1][rr] * acc[1][rr] + acc[2][rr] * acc[2][rr];
        }
        #pragma unroll
        for (int m = 1; m < 16; m <<= 1)
          #pragma unroll
          for (int rr = 0; rr < 4; ++rr) {
              s[rr]  += __shfl_xor(s[rr], m);
              ss[rr] += __shfl_xor(ss[rr], m);
          }
        if (c16 == 0)
          #pragma unroll
          for (int rr = 0; rr < 4; ++rr) {
              Ps[w][4 * g + rr]  = s[rr];
              Pss[w][4 * g + rr] = ss[rr];
          }

        // permuted store: value (nt, rr) -> gate col c = colg + 16nt, row = 4g+rr
        #pragma unroll
        for (int nt = 0; nt < 3; ++nt) {
            int ntg = 3 * w + nt;
            int off = 48 * (ntg & 3) + 12 * (c16 >> 2) + 4 * (ntg >> 2) + (c16 & 3);
            #pragma unroll
            for (int rr = 0; rr < 4; ++rr)
                T[(4 * g + rr) * G_DIM + off] = f2bf(acc[nt][rr]);
        }
        __syncthreads();

        if (tid < 16) {
            float sa  = Ps[0][tid] + Ps[1][tid] + Ps[2][tid] + Ps[3][tid];
            float q2  = Pss[0][tid] + Pss[1][tid] + Pss[2][tid] + Pss[3][tid];
            float m   = sa * (1.f / G_DIM);
            float var = (q2 - (float)G_DIM * m * m) * (1.f / (G_DIM - 1));
            stats[2 * (mrow + tid)]     = m;
            stats[2 * (mrow + tid) + 1] = rsqrtf(fmaxf(var, 1e-24f));
        }
        {
            const unsigned short* src = &T[tid * 12];
            unsigned short* dst = tiw + (size_t)mrow * G_DIM + tid * 12;
            ushort4v v0 = *(const ushort4v*)(src);
            ushort4v v1 = *(const ushort4v*)(src + 4);
            ushort4v v2 = *(const ushort4v*)(src + 8);
            *(ushort4v*)(dst)     = v0;
            *(ushort4v*)(dst + 4) = v1;
            *(ushort4v*)(dst + 8) = v2;
        }
        __syncthreads();
    }
}

// ---------------- recurrent kernel: 4-wave block owns 16 rows via operand-swapped MFMA ----------------
struct TiBuf { ushort4v t0, t1, t2; float2v sv; };

static __device__ __forceinline__ void ti_pf(
    TiBuf& b, const unsigned short* __restrict__ tb, const float* __restrict__ sb, int s2)
{
    int t = (s2 < L_SEQ) ? s2 : (s2 - L_SEQ);
    if (t > L_SEQ - 1) t = L_SEQ - 1;
    const unsigned short* tp = tb + (size_t)t * G_DIM;
    b.t0 = *(const ushort4v*)(tp);
    b.t1 = *(const ushort4v*)(tp + 4);
    b.t2 = *(const ushort4v*)(tp + 8);
    b.sv = *(const float2v*)(sb + 2 * t);
}

template<int PHASE>
static __device__ __forceinline__ void rstep(
    TiBuf& buf, const unsigned short* __restrict__ tb, const float* __restrict__ sb, int s,
    unsigned short (&hs)[2][16][72], float (&sl)[2][16][8],
    const bf16x8 (&awh)[3][2], const float (&bhq)[12],
    float (&hreg)[4], int w, int g, int c16)
{
    BAR();                                  // h'[p] (and prior sl) writes visible

    // consume ti prefetched 2 steps ago; reissue immediately
    float a[12];
    #pragma unroll
    for (int j = 0; j < 4; ++j) {
        a[j]     = bf2f(buf.t0[j]);
        a[j + 4] = bf2f(buf.t1[j]);
        a[j + 8] = bf2f(buf.t2[j]);
    }
    const float mti = buf.sv[0], rti = buf.sv[1];
    ti_pf(buf, tb, sb, s + 2);

    const int p = s & 1;
    bf16x8 h0 = *(const bf16x8*)&hs[p][c16][8 * g];
    bf16x8 h1 = *(const bf16x8*)&hs[p][c16][32 + 8 * g];

    const f32x4 zero = {0.f, 0.f, 0.f, 0.f};
    f32x4 acc0 = __builtin_amdgcn_mfma_f32_16x16x32_bf16(awh[0][0], h0, zero, 0, 0, 0);
    f32x4 acc1 = __builtin_amdgcn_mfma_f32_16x16x32_bf16(awh[1][0], h0, zero, 0, 0, 0);
    f32x4 acc2 = __builtin_amdgcn_mfma_f32_16x16x32_bf16(awh[2][0], h0, zero, 0, 0, 0);
    acc0 = __builtin_amdgcn_mfma_f32_16x16x32_bf16(awh[0][1], h1, acc0, 0, 0, 0);
    acc1 = __builtin_amdgcn_mfma_f32_16x16x32_bf16(awh[1][1], h1, acc1, 0, 0, 0);
    acc2 = __builtin_amdgcn_mfma_f32_16x16x32_bf16(awh[2][1], h1, acc2, 0, 0, 0);

    float b[12];
    #pragma unroll
    for (int rr = 0; rr < 4; ++rr) {
        b[rr]     = acc0[rr] + bhq[rr];
        b[4 + rr] = acc1[rr] + bhq[4 + rr];
        b[8 + rr] = acc2[rr] + bhq[8 + rr];
    }

    float mth = 0.f, rth = 1.f;
    if constexpr (PHASE) {
        float sbv = 0.f, ssv = 0.f;
        #pragma unroll
        for (int k = 0; k < 12; ++k) { sbv += b[k]; ssv = fmaf(b[k], b[k], ssv); }
        sbv += __shfl_xor(sbv, 16); sbv += __shfl_xor(sbv, 32);
        ssv += __shfl_xor(ssv, 16); ssv += __shfl_xor(ssv, 32);
        if (g == 0) {
            sl[p][c16][2 * w]     = sbv;
            sl[p][c16][2 * w + 1] = ssv;
        }
        BAR();                               // sl[p] partials visible
        float4v f0 = *(const float4v*)&sl[p][c16][0];
        float4v f1 = *(const float4v*)&sl[p][c16][4];
        float S  = f0[0] + f0[2] + f1[0] + f1[2];
        float SS = f0[1] + f0[3] + f1[1] + f1[3];
        mth = S * (1.f / G_DIM);
        rth = rsqrtf(fmaxf((SS - (float)G_DIM * mth * mth) * (1.f / (G_DIM - 1)), 1e-24f));
    }

    ushort4v hv;
    #pragma unroll
    for (int rr = 0; rr < 4; ++rr) {
        float tir, tiz, tin, thr, thz, thn;
        if constexpr (PHASE) {
            tir = (a[rr]     - mti) * rti;
            tiz = (a[4 + rr] - mti) * rti;
            tin = (a[8 + rr] - mti) * rti;
            thr = (b[rr]     - mth) * rth;
            thz = (b[4 + rr] - mth) * rth;
            thn = (b[8 + rr] - mth) * rth;
        } else {
            tir = a[rr]; tiz = a[4 + rr]; tin = a[8 + rr];
            thr = b[rr]; thz = b[4 + rr]; thn = b[8 + rr];
        }
        float rt = sigmoidf_(tir + thr);
        float zt = sigmoidf_(tiz + thz);
        float nv = tanhf_(tin + rt * thn);
        hreg[rr] = (1.f - zt) * nv + zt * hreg[rr];
        hv[rr] = f2bf(hreg[rr]);
    }
    *(ushort4v*)&hs[p ^ 1][c16][16 * w + 4 * g] = hv;   // h' for next step
}

__global__ __launch_bounds__(256) void gru_rec_coop(
    const unsigned short* __restrict__ tiw, const float* __restrict__ stats,
    const float* __restrict__ Wh, const float* __restrict__ bh,
    const float* __restrict__ Wfc, const float* __restrict__ bfc,
    float* __restrict__ out)
{
    __shared__ unsigned short hs[2][16][72];   // [parity][batch-row][h-col], stride 144 B (16B-aligned)
    __shared__ float sl[2][16][8];             // [parity][row][w*2 + {s,ss}]

    const int tid = threadIdx.x;
    const int w   = tid >> 6, l = tid & 63;
    const int c16 = l & 15,  g = l >> 4;
    const int row0 = blockIdx.x * 16;

    // A-frags of Wh^T (identical lane values to the old Wh B-frags): tile ntg = w + 4i
    bf16x8 awh[3][2];
    #pragma unroll
    for (int i = 0; i < 3; ++i)
      #pragma unroll
      for (int kt = 0; kt < 2; ++kt)
        #pragma unroll
        for (int j = 0; j < 8; ++j)
            awh[i][kt][j] = (short)f2bf(Wh[(32 * kt + 8 * g + j) * G_DIM + 16 * (w + 4 * i) + c16]);

    float bhq[12];
    #pragma unroll
    for (int i = 0; i < 3; ++i)
      #pragma unroll
      for (int rr = 0; rr < 4; ++rr)
          bhq[4 * i + rr] = bh[16 * (w + 4 * i) + 4 * g + rr];

    // zero h[parity 0]
    {
        bf16x8 z = {0, 0, 0, 0, 0, 0, 0, 0};
        *(bf16x8*)&hs[0][c16][8 * g]      = z;
        *(bf16x8*)&hs[0][c16][32 + 8 * g] = z;
    }

    const unsigned short* tb = tiw + (size_t)(row0 + c16) * L_SEQ * G_DIM + 48 * w + 12 * g;
    const float* sb = stats + (size_t)(row0 + c16) * L_SEQ * 2;

    float hreg[4] = {0.f, 0.f, 0.f, 0.f};
    TiBuf bA, bB;
    ti_pf(bA, tb, sb, 0);
    ti_pf(bB, tb, sb, 1);

    #pragma unroll 1
    for (int s = 0; s < L_SEQ; s += 2) {
        rstep<0>(bA, tb, sb, s,     hs, sl, awh, bhq, hreg, w, g, c16);
        rstep<0>(bB, tb, sb, s + 1, hs, sl, awh, bhq, hreg, w, g, c16);
    }
    #pragma unroll 1
    for (int s = L_SEQ; s < 2 * L_SEQ; s += 2) {
        rstep<1>(bA, tb, sb, s,     hs, sl, awh, bhq, hreg, w, g, c16);
        rstep<1>(bB, tb, sb, s + 1, hs, sl, awh, bhq, hreg, w, g, c16);
    }

    // epilogue: out = h @ W_fc + b_fc
    float p0 = 0.f, p1 = 0.f;
    #pragma unroll
    for (int rr = 0; rr < 4; ++rr) {
        int c = 16 * w + 4 * g + rr;
        p0 = fmaf(hreg[rr], Wfc[2 * c],     p0);
        p1 = fmaf(hreg[rr], Wfc[2 * c + 1], p1);
    }
    p0 += __shfl_xor(p0, 16); p0 += __shfl_xor(p0, 32);
    p1 += __shfl_xor(p1, 16); p1 += __shfl_xor(p1, 32);
    if (g == 0) {
        sl[0][c16][2 * w]     = p0;
        sl[0][c16][2 * w + 1] = p1;
    }
    BAR();
    if (tid < 16) {
        float4v f0 = *(const float4v*)&sl[0][tid][0];
        float4v f1 = *(const float4v*)&sl[0][tid][4];
        out[(row0 + tid) * 2 + 0] = f0[0] + f0[2] + f1[0] + f1[2] + bfc[0];
        out[(row0 + tid) * 2 + 1] = f0[1] + f0[3] + f1[1] + f1[3] + bfc[1];
    }
}

// ---------------- fallback (ws too small): monolithic, ti computed inline ----------------
__global__ __launch_bounds__(256, 4) void gru_rec_fallback(
    const float* __restrict__ x,
    const float* __restrict__ Win, const float* __restrict__ bin,
    const float* __restrict__ Wh,  const float* __restrict__ bh,
    const float* __restrict__ Wfc, const float* __restrict__ bfc,
    float* __restrict__ out)
{
    __shared__ float S_th[16][194];
    __shared__ float S_ti[16][194];
    __shared__ unsigned short h_bf[16][72];
    __shared__ float bh_l[G_DIM], bin_l[G_DIM];

    const int tid = threadIdx.x;
    const int w   = tid >> 6, l = tid & 63;
    const int c16 = l & 15,  g = l >> 4;
    const int colg = w * 48 + c16;
    const int row0 = blockIdx.x * 4;
    const int row  = w, q = l;

    if (tid < G_DIM) { bh_l[tid] = bh[tid]; bin_l[tid] = bin[tid]; }
    for (int i = tid; i < 16 * 72; i += 256) (&h_bf[0][0])[i] = 0;

    bf16x8 bwh[2][3], bwin[4][3];
    #pragma unroll
    for (int kt = 0; kt < 2; ++kt)
      #pragma unroll
      for (int nt = 0; nt < 3; ++nt)
        #pragma unroll
        for (int j = 0; j < 8; ++j)
            bwh[kt][nt][j] = (short)f2bf(Wh[(32 * kt + 8 * g + j) * G_DIM + colg + 16 * nt]);
    #pragma unroll
    for (int kt = 0; kt < 4; ++kt)
      #pragma unroll
      for (int nt = 0; nt < 3; ++nt)
        #pragma unroll
        for (int j = 0; j < 8; ++j) {
            int k = 32 * kt + 8 * g + j;
            float v = (k < E_DIM) ? Win[k * G_DIM + colg + 16 * nt] : 0.f;
            bwin[kt][nt][j] = (short)f2bf(v);
        }
    int xr = row0 + c16; if (xr > B_TOT - 1) xr = B_TOT - 1;
    const float* xlane = x + (size_t)xr * (L_SEQ * E_DIM);

    float hq = 0.f;
    __syncthreads();

    for (int s = 0; s < 2 * L_SEQ; ++s) {
        const int t = (s < L_SEQ) ? s : s - L_SEQ;
        const bool phase = (s >= L_SEQ);

        bf16x8 ah0 = *(const bf16x8*)&h_bf[c16][8 * g];
        bf16x8 ah1 = *(const bf16x8*)&h_bf[c16][32 + 8 * g];
        const f32x4 zero = {0.f, 0.f, 0.f, 0.f};
        f32x4 acch[3], acci[3];
        #pragma unroll
        for (int nt = 0; nt < 3; ++nt) {
            acch[nt] = __builtin_amdgcn_mfma_f32_16x16x32_bf16(ah0, bwh[0][nt], zero,     0, 0, 0);
            acch[nt] = __builtin_amdgcn_mfma_f32_16x16x32_bf16(ah1, bwh[1][nt], acch[nt], 0, 0, 0);
        }
        {
            bf16x8 axx[4];
            const float* xp = xlane + t * E_DIM;
            #pragma unroll
            for (int kt = 0; kt < 4; ++kt) {
                int k0 = 32 * kt + 8 * g;
                float xv[8];
                if (k0 + 7 < E_DIM) {
                    *(float4v*)&xv[0] = *(const float4v*)&xp[k0];
                    *(float4v*)&xv[4] = *(const float4v*)&xp[k0 + 4];
                } else {
                    #pragma unroll
                    for (int j = 0; j < 8; ++j) { int k = k0 + j; xv[j] = (k < E_DIM) ? xp[k] : 0.f; }
                }
                #pragma unroll
                for (int j = 0; j < 8; ++j) axx[kt][j] = (short)f2bf(xv[j]);
            }
            #pragma unroll
            for (int nt = 0; nt < 3; ++nt) {
                acci[nt] = zero;
                #pragma unroll
                for (int kt = 0; kt < 4; ++kt)
                    acci[nt] = __builtin_amdgcn_mfma_f32_16x16x32_bf16(axx[kt], bwin[kt][nt], acci[nt], 0, 0, 0);
            }
        }
        #pragma unroll
        for (int nt = 0; nt < 3; ++nt)
          #pragma unroll
          for (int rr = 0; rr < 4; ++rr) {
              S_th[4 * g + rr][colg + 16 * nt] = acch[nt][rr];
              S_ti[4 * g + rr][colg + 16 * nt] = acci[nt][rr];
          }
        __syncthreads();

        float a[3], b[3];
        #pragma unroll
        for (int i = 0; i < 3; ++i) {
            int c = q + 64 * i;
            a[i] = S_ti[row][c] + bin_l[c];
            b[i] = S_th[row][c] + bh_l[c];
        }
        float mti = 0.f, rti = 1.f, mth = 0.f, rth = 1.f;
        if (phase) {
            float sti = a[0] + a[1] + a[2], ssti = a[0]*a[0] + a[1]*a[1] + a[2]*a[2];
            float sth = b[0] + b[1] + b[2], ssth = b[0]*b[0] + b[1]*b[1] + b[2]*b[2];
            #pragma unroll
            for (int m = 1; m < 64; m <<= 1) {
                sti += __shfl_xor(sti, m); ssti += __shfl_xor(ssti, m);
                sth += __shfl_xor(sth, m); ssth += __shfl_xor(ssth, m);
            }
            mti = sti * (1.f / G_DIM);
            rti = rsqrtf(fmaxf((ssti - (float)G_DIM * mti * mti) * (1.f / (G_DIM - 1)), 1e-24f));
            mth = sth * (1.f / G_DIM);
            rth = rsqrtf(fmaxf((ssth - (float)G_DIM * mth * mth) * (1.f / (G_DIM - 1)), 1e-24f));
        }
        float tir = (a[0] - mti) * rti, tiz = (a[1] - mti) * rti, tin = (a[2] - mti) * rti;
        float thr = (b[0] - mth) * rth, thz = (b[1] - mth) * rth, thn = (b[2] - mth) * rth;
        float rt = sigmoidf_(tir + thr);
        float zt = sigmoidf_(tiz + thz);
        float nv = tanhf_(tin + rt * thn);
        hq = (1.f - zt) * nv + zt * hq;
        h_bf[row][q] = f2bf(hq);
        __syncthreads();
    }

    float p0 = hq * Wfc[2 * q], p1 = hq * Wfc[2 * q + 1];
    #pragma unroll
    for (int m = 1; m < 64; m <<= 1) { p0 += __shfl_xor(p0, m); p1 += __shfl_xor(p1, m); }
    if (q == 0) {
        out[(row0 + row) * 2 + 0] = p0 + bfc[0];
        out[(row0 + row) * 2 + 1] = p1 + bfc[1];
    }
}

extern "C" void kernel_launch(void* const* d_in, const int* in_sizes, int n_in,
                              void* d_out, int out_size, void* d_ws, size_t ws_size,
                              hipStream_t stream) {
    const float* x   = (const float*)d_in[0];
    const float* Win = (const float*)d_in[1];
    const float* bin = (const float*)d_in[2];
    const float* Wh  = (const float*)d_in[3];
    const float* bh  = (const float*)d_in[4];
    const float* Wfc = (const float*)d_in[5];
    const float* bfc = (const float*)d_in[6];
    float* out = (float*)d_out;

    const size_t stats_b = (size_t)B_TOT * L_SEQ * 2 * sizeof(float);              // 3.28 MB
    const size_t tiw_b   = (size_t)B_TOT * L_SEQ * G_DIM * sizeof(unsigned short); // 157.3 MB

    if (ws_size >= stats_b + tiw_b) {
        float* stats = (float*)d_ws;
        unsigned short* tiw = (unsigned short*)((char*)d_ws + stats_b);
        ti_proj64<<<dim3(B_TOT * L_SEQ / 64), dim3(256), 0, stream>>>(x, Win, bin, tiw, stats);
        gru_rec_coop<<<dim3(B_TOT / 16), dim3(256), 0, stream>>>(tiw, stats, Wh, bh, Wfc, bfc, out);
    } else {
        gru_rec_fallback<<<dim3(B_TOT / 4), dim3(256), 0, stream>>>(
            x, Win, bin, Wh, bh, Wfc, bfc, out);
    }
}

// Round 7
// 238.958 us; speedup vs baseline: 1.8631x; 1.1126x over previous
//
#include <hip/hip_runtime.h>

#define L_SEQ 100
#define E_DIM 100
#define G_DIM 192   // 3*H
#define B_TOT 4096

typedef __attribute__((ext_vector_type(8))) short bf16x8;
typedef __attribute__((ext_vector_type(4))) float f32x4;
typedef __attribute__((ext_vector_type(4))) float float4v;
typedef __attribute__((ext_vector_type(4))) unsigned uint4v;
typedef __attribute__((ext_vector_type(2))) unsigned uint2v;

static __device__ __forceinline__ unsigned short f2bf(float f) {
    union { float f; unsigned u; } v; v.f = f;
    unsigned r = v.u + 0x7FFFu + ((v.u >> 16) & 1u);  // RNE
    return (unsigned short)(r >> 16);
}
// HW packed fp32x2 -> bf16x2 (RNE), 1 instr
static __device__ __forceinline__ unsigned cvtpk(float lo, float hi) {
    unsigned r;
    asm("v_cvt_pk_bf16_f32 %0, %1, %2" : "=v"(r) : "v"(lo), "v"(hi));
    return r;
}
static __device__ __forceinline__ bf16x8 as_bf16x8(uint4v u) {
    union { uint4v u; bf16x8 h; } v; v.u = u; return v.h;
}
static __device__ __forceinline__ float sigmoidf_(float x) { return 1.f / (1.f + __expf(-x)); }
static __device__ __forceinline__ float tanhf_(float x)    { return 1.f - 2.f / (__expf(2.f * x) + 1.f); }

// raw barrier: drains LDS ops only (keeps global prefetch in flight — no vmcnt drain)
#define BAR() do { \
    asm volatile("s_waitcnt lgkmcnt(0)" ::: "memory"); \
    __builtin_amdgcn_s_barrier(); \
    asm volatile("" ::: "memory"); \
} while (0)

// 2-step-deep x prefetch: 7 x 16B per lane (e-offsets 8g+{0,4}, 32+8g+{0,4}, 64+8g+{0,4}; tail e=96..99 g==0 only)
struct XBuf { f32x4 v[6]; f32x4 tail; };

static __device__ __forceinline__ void x_pf(
    XBuf& b, const float* __restrict__ xlane, const float* __restrict__ xrow, int s2, bool g0)
{
    int t = (s2 < L_SEQ) ? s2 : (s2 - L_SEQ);
    if (t > L_SEQ - 1) t = L_SEQ - 1;
    const float* p = xlane + t * E_DIM;
    b.v[0] = *(const f32x4*)(p);
    b.v[1] = *(const f32x4*)(p + 4);
    b.v[2] = *(const f32x4*)(p + 32);
    b.v[3] = *(const f32x4*)(p + 36);
    b.v[4] = *(const f32x4*)(p + 64);
    b.v[5] = *(const f32x4*)(p + 68);
    const f32x4 z = {0.f, 0.f, 0.f, 0.f};
    b.tail = g0 ? *(const f32x4*)(xrow + t * E_DIM + 96) : z;
}

template<int PHASE>
static __device__ __forceinline__ void rstep(
    XBuf& xb, const float* __restrict__ xlane, const float* __restrict__ xrow, int s,
    unsigned short (&hs)[2][16][72], float (&sl)[2][16][4][4],
    const bf16x8 (&awin)[3][4], const bf16x8 (&awh)[3][2],
    const float (&binq)[12], const float (&bhq)[12],
    float (&hreg)[4], int w, int g, int c16, bool g0)
{
    // ---- pre-barrier: consume x prefetched 2 steps ago, build B-frags, reissue ----
    bf16x8 bx0 = as_bf16x8((uint4v){cvtpk(xb.v[0][0], xb.v[0][1]), cvtpk(xb.v[0][2], xb.v[0][3]),
                                    cvtpk(xb.v[1][0], xb.v[1][1]), cvtpk(xb.v[1][2], xb.v[1][3])});
    bf16x8 bx1 = as_bf16x8((uint4v){cvtpk(xb.v[2][0], xb.v[2][1]), cvtpk(xb.v[2][2], xb.v[2][3]),
                                    cvtpk(xb.v[3][0], xb.v[3][1]), cvtpk(xb.v[3][2], xb.v[3][3])});
    bf16x8 bx2 = as_bf16x8((uint4v){cvtpk(xb.v[4][0], xb.v[4][1]), cvtpk(xb.v[4][2], xb.v[4][3]),
                                    cvtpk(xb.v[5][0], xb.v[5][1]), cvtpk(xb.v[5][2], xb.v[5][3])});
    bf16x8 bx3 = as_bf16x8((uint4v){cvtpk(xb.tail[0], xb.tail[1]), cvtpk(xb.tail[2], xb.tail[3]),
                                    0u, 0u});
    x_pf(xb, xlane, xrow, s + 2, g0);

    BAR();                                  // h'[p] writes visible

    const int p = s & 1;
    bf16x8 h0 = *(const bf16x8*)&hs[p][c16][8 * g];
    bf16x8 h1 = *(const bf16x8*)&hs[p][c16][32 + 8 * g];

    const f32x4 zero = {0.f, 0.f, 0.f, 0.f};
    // ti = Win^T . X   (12 MFMA, 3 independent chains of 4)
    f32x4 ti0 = __builtin_amdgcn_mfma_f32_16x16x32_bf16(awin[0][0], bx0, zero, 0, 0, 0);
    f32x4 ti1 = __builtin_amdgcn_mfma_f32_16x16x32_bf16(awin[1][0], bx0, zero, 0, 0, 0);
    f32x4 ti2 = __builtin_amdgcn_mfma_f32_16x16x32_bf16(awin[2][0], bx0, zero, 0, 0, 0);
    ti0 = __builtin_amdgcn_mfma_f32_16x16x32_bf16(awin[0][1], bx1, ti0, 0, 0, 0);
    ti1 = __builtin_amdgcn_mfma_f32_16x16x32_bf16(awin[1][1], bx1, ti1, 0, 0, 0);
    ti2 = __builtin_amdgcn_mfma_f32_16x16x32_bf16(awin[2][1], bx1, ti2, 0, 0, 0);
    ti0 = __builtin_amdgcn_mfma_f32_16x16x32_bf16(awin[0][2], bx2, ti0, 0, 0, 0);
    ti1 = __builtin_amdgcn_mfma_f32_16x16x32_bf16(awin[1][2], bx2, ti1, 0, 0, 0);
    ti2 = __builtin_amdgcn_mfma_f32_16x16x32_bf16(awin[2][2], bx2, ti2, 0, 0, 0);
    ti0 = __builtin_amdgcn_mfma_f32_16x16x32_bf16(awin[0][3], bx3, ti0, 0, 0, 0);
    ti1 = __builtin_amdgcn_mfma_f32_16x16x32_bf16(awin[1][3], bx3, ti1, 0, 0, 0);
    ti2 = __builtin_amdgcn_mfma_f32_16x16x32_bf16(awin[2][3], bx3, ti2, 0, 0, 0);
    // th = Wh^T . H    (6 MFMA)
    f32x4 th0 = __builtin_amdgcn_mfma_f32_16x16x32_bf16(awh[0][0], h0, zero, 0, 0, 0);
    f32x4 th1 = __builtin_amdgcn_mfma_f32_16x16x32_bf16(awh[1][0], h0, zero, 0, 0, 0);
    f32x4 th2 = __builtin_amdgcn_mfma_f32_16x16x32_bf16(awh[2][0], h0, zero, 0, 0, 0);
    th0 = __builtin_amdgcn_mfma_f32_16x16x32_bf16(awh[0][1], h1, th0, 0, 0, 0);
    th1 = __builtin_amdgcn_mfma_f32_16x16x32_bf16(awh[1][1], h1, th1, 0, 0, 0);
    th2 = __builtin_amdgcn_mfma_f32_16x16x32_bf16(awh[2][1], h1, th2, 0, 0, 0);

    float a[12], b[12];
    #pragma unroll
    for (int rr = 0; rr < 4; ++rr) {
        a[rr]     = ti0[rr] + binq[rr];
        a[4 + rr] = ti1[rr] + binq[4 + rr];
        a[8 + rr] = ti2[rr] + binq[8 + rr];
        b[rr]     = th0[rr] + bhq[rr];
        b[4 + rr] = th1[rr] + bhq[4 + rr];
        b[8 + rr] = th2[rr] + bhq[8 + rr];
    }

    float mti = 0.f, rti = 1.f, mth = 0.f, rth = 1.f;
    if constexpr (PHASE) {
        float sti = 0.f, ssti = 0.f, sth = 0.f, ssth = 0.f;
        #pragma unroll
        for (int k = 0; k < 12; ++k) {
            sti += a[k]; ssti = fmaf(a[k], a[k], ssti);
            sth += b[k]; ssth = fmaf(b[k], b[k], ssth);
        }
        sti += __shfl_xor(sti, 16); sti += __shfl_xor(sti, 32);
        ssti += __shfl_xor(ssti, 16); ssti += __shfl_xor(ssti, 32);
        sth += __shfl_xor(sth, 16); sth += __shfl_xor(sth, 32);
        ssth += __shfl_xor(ssth, 16); ssth += __shfl_xor(ssth, 32);
        if (g == 0) {
            float4v v = {sti, ssti, sth, ssth};
            *(float4v*)&sl[p][c16][w][0] = v;
        }
        BAR();                               // sl[p] partials visible
        float4v q0 = *(const float4v*)&sl[p][c16][0][0];
        float4v q1 = *(const float4v*)&sl[p][c16][1][0];
        float4v q2 = *(const float4v*)&sl[p][c16][2][0];
        float4v q3 = *(const float4v*)&sl[p][c16][3][0];
        float S_ti  = q0[0] + q1[0] + q2[0] + q3[0];
        float SS_ti = q0[1] + q1[1] + q2[1] + q3[1];
        float S_th  = q0[2] + q1[2] + q2[2] + q3[2];
        float SS_th = q0[3] + q1[3] + q2[3] + q3[3];
        mti = S_ti * (1.f / G_DIM);
        rti = rsqrtf(fmaxf((SS_ti - (float)G_DIM * mti * mti) * (1.f / (G_DIM - 1)), 1e-24f));
        mth = S_th * (1.f / G_DIM);
        rth = rsqrtf(fmaxf((SS_th - (float)G_DIM * mth * mth) * (1.f / (G_DIM - 1)), 1e-24f));
    }

    float hn[4];
    #pragma unroll
    for (int rr = 0; rr < 4; ++rr) {
        float tir, tiz, tin, thr, thz, thn;
        if constexpr (PHASE) {
            tir = (a[rr]     - mti) * rti;
            tiz = (a[4 + rr] - mti) * rti;
            tin = (a[8 + rr] - mti) * rti;
            thr = (b[rr]     - mth) * rth;
            thz = (b[4 + rr] - mth) * rth;
            thn = (b[8 + rr] - mth) * rth;
        } else {
            tir = a[rr]; tiz = a[4 + rr]; tin = a[8 + rr];
            thr = b[rr]; thz = b[4 + rr]; thn = b[8 + rr];
        }
        float rt = sigmoidf_(tir + thr);
        float zt = sigmoidf_(tiz + thz);
        float nv = tanhf_(tin + rt * thn);
        hn[rr] = (1.f - zt) * nv + zt * hreg[rr];
        hreg[rr] = hn[rr];
    }
    uint2v hv = { cvtpk(hn[0], hn[1]), cvtpk(hn[2], hn[3]) };
    *(uint2v*)&hs[p ^ 1][c16][16 * w + 4 * g] = hv;   // h' for next step
}

__global__ __launch_bounds__(256, 1) void gru_fused(
    const float* __restrict__ x,
    const float* __restrict__ Win, const float* __restrict__ bin,
    const float* __restrict__ Wh,  const float* __restrict__ bh,
    const float* __restrict__ Wfc, const float* __restrict__ bfc,
    float* __restrict__ out)
{
    __shared__ unsigned short hs[2][16][72];   // [parity][batch-row][h-dim]
    __shared__ float sl[2][16][4][4];          // [parity][row][wave]{s_ti,ss_ti,s_th,ss_th}

    const int tid = threadIdx.x;
    const int w   = tid >> 6, l = tid & 63;
    const int c16 = l & 15,  g = l >> 4;
    const bool g0 = (g == 0);
    const int row0 = blockIdx.x * 16;

    // A-frags of Win^T (12) and Wh^T (6), register-resident; tile ntg = w + 4i
    bf16x8 awin[3][4];
    #pragma unroll
    for (int i = 0; i < 3; ++i)
      #pragma unroll
      for (int kt = 0; kt < 4; ++kt)
        #pragma unroll
        for (int j = 0; j < 8; ++j) {
            int k = 32 * kt + 8 * g + j;
            float v = (k < E_DIM) ? Win[k * G_DIM + 16 * (w + 4 * i) + c16] : 0.f;
            awin[i][kt][j] = (short)f2bf(v);
        }
    bf16x8 awh[3][2];
    #pragma unroll
    for (int i = 0; i < 3; ++i)
      #pragma unroll
      for (int kt = 0; kt < 2; ++kt)
        #pragma unroll
        for (int j = 0; j < 8; ++j)
            awh[i][kt][j] = (short)f2bf(Wh[(32 * kt + 8 * g + j) * G_DIM + 16 * (w + 4 * i) + c16]);

    float binq[12], bhq[12];
    #pragma unroll
    for (int i = 0; i < 3; ++i)
      #pragma unroll
      for (int rr = 0; rr < 4; ++rr) {
          binq[4 * i + rr] = bin[16 * (w + 4 * i) + 4 * g + rr];
          bhq[4 * i + rr]  = bh[16 * (w + 4 * i) + 4 * g + rr];
      }

    // zero h[parity 0]
    {
        bf16x8 z = {0, 0, 0, 0, 0, 0, 0, 0};
        *(bf16x8*)&hs[0][c16][8 * g]      = z;
        *(bf16x8*)&hs[0][c16][32 + 8 * g] = z;
    }

    const float* xrow  = x + (size_t)(row0 + c16) * (L_SEQ * E_DIM);
    const float* xlane = xrow + 8 * g;

    float hreg[4] = {0.f, 0.f, 0.f, 0.f};
    XBuf xA, xB;
    x_pf(xA, xlane, xrow, 0, g0);
    x_pf(xB, xlane, xrow, 1, g0);

    #pragma unroll 1
    for (int s = 0; s < L_SEQ; s += 2) {
        rstep<0>(xA, xlane, xrow, s,     hs, sl, awin, awh, binq, bhq, hreg, w, g, c16, g0);
        rstep<0>(xB, xlane, xrow, s + 1, hs, sl, awin, awh, binq, bhq, hreg, w, g, c16, g0);
    }
    #pragma unroll 1
    for (int s = L_SEQ; s < 2 * L_SEQ; s += 2) {
        rstep<1>(xA, xlane, xrow, s,     hs, sl, awin, awh, binq, bhq, hreg, w, g, c16, g0);
        rstep<1>(xB, xlane, xrow, s + 1, hs, sl, awin, awh, binq, bhq, hreg, w, g, c16, g0);
    }

    // epilogue: out = h @ W_fc + b_fc
    float p0 = 0.f, p1 = 0.f;
    #pragma unroll
    for (int rr = 0; rr < 4; ++rr) {
        int c = 16 * w + 4 * g + rr;
        p0 = fmaf(hreg[rr], Wfc[2 * c],     p0);
        p1 = fmaf(hreg[rr], Wfc[2 * c + 1], p1);
    }
    p0 += __shfl_xor(p0, 16); p0 += __shfl_xor(p0, 32);
    p1 += __shfl_xor(p1, 16); p1 += __shfl_xor(p1, 32);
    if (g == 0) {
        sl[0][c16][w][0] = p0;
        sl[0][c16][w][1] = p1;
    }
    BAR();
    if (tid < 16) {
        out[(row0 + tid) * 2 + 0] = sl[0][tid][0][0] + sl[0][tid][1][0] + sl[0][tid][2][0] + sl[0][tid][3][0] + bfc[0];
        out[(row0 + tid) * 2 + 1] = sl[0][tid][0][1] + sl[0][tid][1][1] + sl[0][tid][2][1] + sl[0][tid][3][1] + bfc[1];
    }
}

extern "C" void kernel_launch(void* const* d_in, const int* in_sizes, int n_in,
                              void* d_out, int out_size, void* d_ws, size_t ws_size,
                              hipStream_t stream) {
    const float* x   = (const float*)d_in[0];
    const float* Win = (const float*)d_in[1];
    const float* bin = (const float*)d_in[2];
    const float* Wh  = (const float*)d_in[3];
    const float* bh  = (const float*)d_in[4];
    const float* Wfc = (const float*)d_in[5];
    const float* bfc = (const float*)d_in[6];
    float* out = (float*)d_out;
    gru_fused<<<dim3(B_TOT / 16), dim3(256), 0, stream>>>(
        x, Win, bin, Wh, bh, Wfc, bfc, out);
}

// Round 8
// 201.277 us; speedup vs baseline: 2.2119x; 1.1872x over previous
//
#include <hip/hip_runtime.h>

#define L_SEQ 100
#define E_DIM 100
#define G_DIM 192   // 3*H
#define B_TOT 4096

typedef __attribute__((ext_vector_type(8))) short bf16x8;
typedef __attribute__((ext_vector_type(4))) float f32x4;
typedef __attribute__((ext_vector_type(4))) float float4v;
typedef __attribute__((ext_vector_type(2))) float float2v;
typedef __attribute__((ext_vector_type(4))) unsigned uint4v;
typedef __attribute__((ext_vector_type(2))) unsigned uint2v;

#define MFMA16 __builtin_amdgcn_mfma_f32_16x16x32_bf16

static __device__ __forceinline__ unsigned short f2bf(float f) {
    union { float f; unsigned u; } v; v.f = f;
    unsigned r = v.u + 0x7FFFu + ((v.u >> 16) & 1u);  // RNE
    return (unsigned short)(r >> 16);
}
static __device__ __forceinline__ unsigned cvtpk(float lo, float hi) {
    unsigned r;
    asm("v_cvt_pk_bf16_f32 %0, %1, %2" : "=v"(r) : "v"(lo), "v"(hi));
    return r;
}
static __device__ __forceinline__ bf16x8 as_bf16x8(uint4v u) {
    union { uint4v u; bf16x8 h; } v; v.u = u; return v.h;
}
static __device__ __forceinline__ float rcpf_(float x) { return __builtin_amdgcn_rcpf(x); }

// raw barrier: drains LDS ops only (keeps global prefetch in flight — no vmcnt drain)
#define BAR() do { \
    asm volatile("s_waitcnt lgkmcnt(0)" ::: "memory"); \
    __builtin_amdgcn_s_barrier(); \
    asm volatile("" ::: "memory"); \
} while (0)

struct XBuf { f32x4 v[6]; f32x4 tail; };

static __device__ __forceinline__ int tmod(int c) {
    int t = c;
    if (t >= L_SEQ) t -= L_SEQ;
    if (t >= L_SEQ) t -= L_SEQ;
    return t;
}

static __device__ __forceinline__ void x_pf(
    XBuf& b, const float* __restrict__ xlane, const float* __restrict__ xrow, int c, bool g0)
{
    const int t = tmod(c);
    const float* p = xlane + t * E_DIM;
    b.v[0] = *(const f32x4*)(p);
    b.v[1] = *(const f32x4*)(p + 4);
    b.v[2] = *(const f32x4*)(p + 32);
    b.v[3] = *(const f32x4*)(p + 36);
    b.v[4] = *(const f32x4*)(p + 64);
    b.v[5] = *(const f32x4*)(p + 68);
    const f32x4 z = {0.f, 0.f, 0.f, 0.f};
    b.tail = g0 ? *(const f32x4*)(xrow + t * E_DIM + 96) : z;
}

// ti-wave: compute ti[c] = x[c]@Win + bin, write to LDS ring + stat partials
static __device__ __forceinline__ void produce(
    XBuf& xb, const float* __restrict__ xlane, const float* __restrict__ xrow,
    int c, bool g0, float* __restrict__ tird, float* __restrict__ sltiw,
    const bf16x8 (&awin)[3][4], const float (&binq)[12])
{
    bf16x8 bx0 = as_bf16x8((uint4v){cvtpk(xb.v[0][0], xb.v[0][1]), cvtpk(xb.v[0][2], xb.v[0][3]),
                                    cvtpk(xb.v[1][0], xb.v[1][1]), cvtpk(xb.v[1][2], xb.v[1][3])});
    bf16x8 bx1 = as_bf16x8((uint4v){cvtpk(xb.v[2][0], xb.v[2][1]), cvtpk(xb.v[2][2], xb.v[2][3]),
                                    cvtpk(xb.v[3][0], xb.v[3][1]), cvtpk(xb.v[3][2], xb.v[3][3])});
    bf16x8 bx2 = as_bf16x8((uint4v){cvtpk(xb.v[4][0], xb.v[4][1]), cvtpk(xb.v[4][2], xb.v[4][3]),
                                    cvtpk(xb.v[5][0], xb.v[5][1]), cvtpk(xb.v[5][2], xb.v[5][3])});
    bf16x8 bx3 = as_bf16x8((uint4v){cvtpk(xb.tail[0], xb.tail[1]), cvtpk(xb.tail[2], xb.tail[3]),
                                    0u, 0u});
    x_pf(xb, xlane, xrow, c + 2, g0);   // reissue this buffer 2 steps ahead

    const f32x4 zero = {0.f, 0.f, 0.f, 0.f};
    f32x4 t0 = MFMA16(awin[0][0], bx0, zero, 0, 0, 0);
    f32x4 t1 = MFMA16(awin[1][0], bx0, zero, 0, 0, 0);
    f32x4 t2 = MFMA16(awin[2][0], bx0, zero, 0, 0, 0);
    t0 = MFMA16(awin[0][1], bx1, t0, 0, 0, 0);
    t1 = MFMA16(awin[1][1], bx1, t1, 0, 0, 0);
    t2 = MFMA16(awin[2][1], bx1, t2, 0, 0, 0);
    t0 = MFMA16(awin[0][2], bx2, t0, 0, 0, 0);
    t1 = MFMA16(awin[1][2], bx2, t1, 0, 0, 0);
    t2 = MFMA16(awin[2][2], bx2, t2, 0, 0, 0);
    t0 = MFMA16(awin[0][3], bx3, t0, 0, 0, 0);
    t1 = MFMA16(awin[1][3], bx3, t1, 0, 0, 0);
    t2 = MFMA16(awin[2][3], bx3, t2, 0, 0, 0);

    const int par = c & 1;
    float4v A0 = {t0[0] + binq[0], t0[1] + binq[1], t0[2] + binq[2],  t0[3] + binq[3]};
    float4v A1 = {t1[0] + binq[4], t1[1] + binq[5], t1[2] + binq[6],  t1[3] + binq[7]};
    float4v A2 = {t2[0] + binq[8], t2[1] + binq[9], t2[2] + binq[10], t2[3] + binq[11]};
    float* dst = tird + par * 3328;     // parity stride = 4*16*52 floats
    *(float4v*)(dst)     = A0;
    *(float4v*)(dst + 4) = A1;
    *(float4v*)(dst + 8) = A2;

    float s = ((A0[0] + A0[1]) + (A0[2] + A0[3])) + ((A1[0] + A1[1]) + (A1[2] + A1[3]))
            + ((A2[0] + A2[1]) + (A2[2] + A2[3]));
    float ss = 0.f;
    #pragma unroll
    for (int k2 = 0; k2 < 4; ++k2) ss = fmaf(A0[k2], A0[k2], ss);
    #pragma unroll
    for (int k2 = 0; k2 < 4; ++k2) ss = fmaf(A1[k2], A1[k2], ss);
    #pragma unroll
    for (int k2 = 0; k2 < 4; ++k2) ss = fmaf(A2[k2], A2[k2], ss);
    s  += __shfl_xor(s, 16);  s  += __shfl_xor(s, 32);
    ss += __shfl_xor(ss, 16); ss += __shfl_xor(ss, 32);
    if (g0) *(float2v*)(sltiw + par * 192) = (float2v){s, ss};
}

__global__ __launch_bounds__(512, 1) void gru_ws(
    const float* __restrict__ x,
    const float* __restrict__ Win, const float* __restrict__ bin,
    const float* __restrict__ Wh,  const float* __restrict__ bh,
    const float* __restrict__ Wfc, const float* __restrict__ bfc,
    float* __restrict__ out)
{
    __shared__ __align__(16) unsigned short hs[2][16][72];   // h ring [parity][row][hdim]
    __shared__ __align__(16) float tir[2][4][16][52];        // ti ring [parity][w][row][g*12+i*4+rr]
    __shared__ __align__(16) float slti[2][16][12];          // ti stat partials {s,ss} per wave
    __shared__ __align__(16) float slth[2][16][12];          // th stat partials

    const int tid = threadIdx.x;
    const int wv  = tid >> 6;
    const int w   = wv & 3;                 // role-local wave index (ntg group)
    const bool tirole = (wv >= 4);
    const int l = tid & 63, c16 = l & 15, g = l >> 4;
    const bool g0 = (g == 0);
    const int row0 = blockIdx.x * 16;

    bf16x8 awin[3][4]; float binq[12];
    bf16x8 awh[3][2];  float bhq[12];
    const float* xrow = nullptr; const float* xlane = nullptr;

    if (tirole) {
        #pragma unroll
        for (int i = 0; i < 3; ++i)
          #pragma unroll
          for (int kt = 0; kt < 4; ++kt)
            #pragma unroll
            for (int j = 0; j < 8; ++j) {
                int k = 32 * kt + 8 * g + j;
                float v = (k < E_DIM) ? Win[k * G_DIM + 16 * (w + 4 * i) + c16] : 0.f;
                awin[i][kt][j] = (short)f2bf(v);
            }
        #pragma unroll
        for (int i = 0; i < 3; ++i)
          #pragma unroll
          for (int rr = 0; rr < 4; ++rr)
              binq[4 * i + rr] = bin[16 * (w + 4 * i) + 4 * g + rr];
        xrow  = x + (size_t)(row0 + c16) * (L_SEQ * E_DIM);
        xlane = xrow + 8 * g;
    } else {
        #pragma unroll
        for (int i = 0; i < 3; ++i)
          #pragma unroll
          for (int kt = 0; kt < 2; ++kt)
            #pragma unroll
            for (int j = 0; j < 8; ++j)
                awh[i][kt][j] = (short)f2bf(Wh[(32 * kt + 8 * g + j) * G_DIM + 16 * (w + 4 * i) + c16]);
        #pragma unroll
        for (int i = 0; i < 3; ++i)
          #pragma unroll
          for (int rr = 0; rr < 4; ++rr)
              bhq[4 * i + rr] = bh[16 * (w + 4 * i) + 4 * g + rr];
        bf16x8 z = {0, 0, 0, 0, 0, 0, 0, 0};
        *(bf16x8*)&hs[0][c16][8 * g]      = z;
        *(bf16x8*)&hs[0][c16][32 + 8 * g] = z;
    }

    float* tird        = &tir[0][w][c16][g * 12];
    float* sltiw       = &slti[0][c16][2 * w];
    float* slthw       = &slth[0][c16][2 * w];
    const float* sltir = &slti[0][c16][0];
    const float* slthr = &slth[0][c16][0];

    float hreg[4] = {0.f, 0.f, 0.f, 0.f};

    XBuf xA, xB;
    if (tirole) {
        x_pf(xA, xlane, xrow, 0, g0);
        x_pf(xB, xlane, xrow, 1, g0);
        produce(xA, xlane, xrow, 0, g0, tird, sltiw, awin, binq);   // ti[0]; reissues A for c=2
    }
    BAR();
    if (!tirole) __builtin_amdgcn_s_setprio(1);   // favor the recurrent critical path (T5)

    auto HGEMM = [&](int par, float4v& a0, float4v& a1, float4v& a2, float (&b)[12]) {
        const float* src = tird + par * 3328;
        a0 = *(const float4v*)(src);
        a1 = *(const float4v*)(src + 4);
        a2 = *(const float4v*)(src + 8);
        bf16x8 h0 = *(const bf16x8*)&hs[par][c16][8 * g];
        bf16x8 h1 = *(const bf16x8*)&hs[par][c16][32 + 8 * g];
        const f32x4 zero = {0.f, 0.f, 0.f, 0.f};
        f32x4 t0 = MFMA16(awh[0][0], h0, zero, 0, 0, 0);
        f32x4 t1 = MFMA16(awh[1][0], h0, zero, 0, 0, 0);
        f32x4 t2 = MFMA16(awh[2][0], h0, zero, 0, 0, 0);
        t0 = MFMA16(awh[0][1], h1, t0, 0, 0, 0);
        t1 = MFMA16(awh[1][1], h1, t1, 0, 0, 0);
        t2 = MFMA16(awh[2][1], h1, t2, 0, 0, 0);
        #pragma unroll
        for (int rr = 0; rr < 4; ++rr) {
            b[rr]     = t0[rr] + bhq[rr];
            b[4 + rr] = t1[rr] + bhq[4 + rr];
            b[8 + rr] = t2[rr] + bhq[8 + rr];
        }
    };
    auto HWRITE = [&](int par, float (&hn)[4]) {
        *(uint2v*)&hs[par ^ 1][c16][16 * w + 4 * g] = (uint2v){cvtpk(hn[0], hn[1]), cvtpk(hn[2], hn[3])};
    };

    // ---------------- phase 1: no norm, 1 barrier/step ----------------
    #pragma unroll 1
    for (int s = 0; s < L_SEQ; s += 2) {
        #pragma unroll
        for (int sub = 0; sub < 2; ++sub) {
            const int st = s + sub;
            XBuf& X = sub ? xA : xB;
            if (tirole) {
                produce(X, xlane, xrow, st + 1, g0, tird, sltiw, awin, binq);
            } else {
                const int par = st & 1;
                float4v a0, a1, a2; float b[12];
                HGEMM(par, a0, a1, a2, b);
                float hn[4];
                #pragma unroll
                for (int rr = 0; rr < 4; ++rr) {
                    float er = rcpf_(1.f + __expf(-(a0[rr] + b[rr])));
                    float zt = rcpf_(1.f + __expf(-(a1[rr] + b[4 + rr])));
                    float u  = fmaf(er, b[8 + rr], a2[rr]);
                    float tn = fmaf(2.f, rcpf_(1.f + __expf(-2.f * u)), -1.f);
                    hn[rr] = fmaf(zt, hreg[rr] - tn, tn);
                    hreg[rr] = hn[rr];
                }
                HWRITE(par, hn);
            }
            BAR();
        }
    }

    // ---------------- phase 2: vector norm, 2 barriers/step ----------------
    #pragma unroll 1
    for (int s = L_SEQ; s < 2 * L_SEQ; s += 2) {
        #pragma unroll
        for (int sub = 0; sub < 2; ++sub) {
            const int st = s + sub;
            XBuf& X = sub ? xA : xB;
            const int par = st & 1;
            float4v a0, a1, a2; float b[12];
            if (tirole) {
                produce(X, xlane, xrow, st + 1, g0, tird, sltiw, awin, binq);
            } else {
                HGEMM(par, a0, a1, a2, b);
                float sb = 0.f, ssb = 0.f;
                #pragma unroll
                for (int k2 = 0; k2 < 12; ++k2) { sb += b[k2]; ssb = fmaf(b[k2], b[k2], ssb); }
                sb  += __shfl_xor(sb, 16);  sb  += __shfl_xor(sb, 32);
                ssb += __shfl_xor(ssb, 16); ssb += __shfl_xor(ssb, 32);
                if (g0) *(float2v*)(slthw + par * 192) = (float2v){sb, ssb};
            }
            BAR();   // mid: th partials visible (ti stats were published a step earlier)
            if (!tirole) {
                const float* sp = slthr + par * 192;
                float4v q0 = *(const float4v*)(sp);
                float4v q1 = *(const float4v*)(sp + 4);
                const float* ip = sltir + par * 192;
                float4v r0 = *(const float4v*)(ip);
                float4v r1 = *(const float4v*)(ip + 4);
                float Sth  = (q0[0] + q0[2]) + (q1[0] + q1[2]);
                float SSth = (q0[1] + q0[3]) + (q1[1] + q1[3]);
                float Sti  = (r0[0] + r0[2]) + (r1[0] + r1[2]);
                float SSti = (r0[1] + r0[3]) + (r1[1] + r1[3]);
                float mth = Sth * (1.f / G_DIM);
                float rth = __builtin_amdgcn_rsqf(
                    fmaxf((SSth - (float)G_DIM * mth * mth) * (1.f / (G_DIM - 1)), 1e-24f));
                float mti = Sti * (1.f / G_DIM);
                float rti = __builtin_amdgcn_rsqf(
                    fmaxf((SSti - (float)G_DIM * mti * mti) * (1.f / (G_DIM - 1)), 1e-24f));
                float mrti = mti * rti, mrth = mth * rth;
                float Cn = mrti + mrth;   // sigmoid arg: -x = -a*rti - b*rth + Cn (2 fma)
                float hn[4];
                #pragma unroll
                for (int rr = 0; rr < 4; ++rr) {
                    float mr = fmaf(a0[rr], -rti, fmaf(b[rr],     -rth, Cn));
                    float er = rcpf_(1.f + __expf(mr));
                    float mz = fmaf(a1[rr], -rti, fmaf(b[4 + rr], -rth, Cn));
                    float zt = rcpf_(1.f + __expf(mz));
                    float ni = fmaf(a2[rr],     rti, -mrti);
                    float nh = fmaf(b[8 + rr],  rth, -mrth);
                    float u  = fmaf(er, nh, ni);
                    float tn = fmaf(2.f, rcpf_(1.f + __expf(-2.f * u)), -1.f);
                    hn[rr] = fmaf(zt, hreg[rr] - tn, tn);
                    hreg[rr] = hn[rr];
                }
                HWRITE(par, hn);
            }
            BAR();   // end: h' visible
        }
    }

    // ---------------- epilogue: out = h @ W_fc + b_fc ----------------
    if (!tirole) {
        float po0 = 0.f, po1 = 0.f;
        #pragma unroll
        for (int rr = 0; rr < 4; ++rr) {
            int c = 16 * w + 4 * g + rr;
            po0 = fmaf(hreg[rr], Wfc[2 * c],     po0);
            po1 = fmaf(hreg[rr], Wfc[2 * c + 1], po1);
        }
        po0 += __shfl_xor(po0, 16); po0 += __shfl_xor(po0, 32);
        po1 += __shfl_xor(po1, 16); po1 += __shfl_xor(po1, 32);
        if (g0) *(float2v*)(slthw) = (float2v){po0, po1};
    }
    BAR();
    if (tid < 16) {
        const float* sp = &slth[0][tid][0];
        float4v q0 = *(const float4v*)(sp);
        float4v q1 = *(const float4v*)(sp + 4);
        out[(row0 + tid) * 2 + 0] = (q0[0] + q0[2]) + (q1[0] + q1[2]) + bfc[0];
        out[(row0 + tid) * 2 + 1] = (q0[1] + q0[3]) + (q1[1] + q1[3]) + bfc[1];
    }
}

extern "C" void kernel_launch(void* const* d_in, const int* in_sizes, int n_in,
                              void* d_out, int out_size, void* d_ws, size_t ws_size,
                              hipStream_t stream) {
    const float* x   = (const float*)d_in[0];
    const float* Win = (const float*)d_in[1];
    const float* bin = (const float*)d_in[2];
    const float* Wh  = (const float*)d_in[3];
    const float* bh  = (const float*)d_in[4];
    const float* Wfc = (const float*)d_in[5];
    const float* bfc = (const float*)d_in[6];
    float* out = (float*)d_out;
    gru_ws<<<dim3(B_TOT / 16), dim3(512), 0, stream>>>(
        x, Win, bin, Wh, bh, Wfc, bfc, out);
}